// Round 1
// baseline (3418.514 us; speedup 1.0000x reference)
//
#include <hip/hip_runtime.h>

#define NN 50000
#define NE 1600000
#define HID 128

// ---------------- CSR build ----------------

__global__ __launch_bounds__(256) void k_hist(const int* __restrict__ dst,
                                              int* __restrict__ deg, int E) {
  int i = blockIdx.x * 256 + threadIdx.x;
  if (i < E) atomicAdd(&deg[dst[i]], 1);
}

__global__ __launch_bounds__(1024) void k_scan(const int* __restrict__ deg,
                                               int* __restrict__ rs,
                                               int* __restrict__ cursor, int M) {
  __shared__ int part[1024];
  int tid = threadIdx.x;
  int chunk = (M + 1023) >> 10;
  int lo = tid * chunk;
  int hi = min(lo + chunk, M);
  int s = 0;
  for (int i = lo; i < hi; ++i) s += deg[i];
  part[tid] = s;
  __syncthreads();
  int own = s;
  for (int d = 1; d < 1024; d <<= 1) {
    int t = (tid >= d) ? part[tid - d] : 0;
    __syncthreads();
    part[tid] += t;
    __syncthreads();
  }
  int run = part[tid] - own;  // exclusive prefix
  for (int i = lo; i < hi; ++i) {
    rs[i] = run;
    cursor[i] = run;
    run += deg[i];
  }
  if (tid == 1023) rs[M] = part[1023];
}

__global__ __launch_bounds__(256) void k_scatter(const int* __restrict__ src,
                                                 const int* __restrict__ dst,
                                                 int* __restrict__ cursor,
                                                 int* __restrict__ eidx, int E) {
  int i = blockIdx.x * 256 + threadIdx.x;
  if (i < E) {
    int d = dst[i];
    int p = atomicAdd(&cursor[d], 1);
    eidx[p] = src[i];
  }
}

// ---------------- aggregation: z = (1+eps)*h + sum_{e: dst=node} h[src_e] --------

__global__ __launch_bounds__(256) void k_agg(const float* __restrict__ h,
                                             const int* __restrict__ rs,
                                             const int* __restrict__ eidx,
                                             const float* __restrict__ eps, int layer,
                                             float* __restrict__ z, int M) {
  int node = (int)((blockIdx.x * 256 + threadIdx.x) >> 6);  // one wave per node
  int lane = threadIdx.x & 63;
  if (node >= M) return;
  float ep = 1.0f + eps[layer];
  const float2* h2 = (const float2*)h;
  int e0 = rs[node], e1 = rs[node + 1];
  float ax = 0.f, ay = 0.f;
  for (int e = e0; e < e1; ++e) {
    int s = eidx[e];
    float2 v = h2[(size_t)s * 64 + lane];
    ax += v.x;
    ay += v.y;
  }
  float2 hv = h2[(size_t)node * 64 + lane];
  float2 o;
  o.x = fmaf(ep, hv.x, ax);
  o.y = fmaf(ep, hv.y, ay);
  ((float2*)z)[(size_t)node * 64 + lane] = o;
}

// ---------------- row-wise GEMM (K=128), optional BN-relu input transform,
//                  optional relu output, optional column-stats accumulation ----

__device__ __forceinline__ void fma4(float4& a, const float4& v, const float4& w0,
                                     const float4& w1, const float4& w2,
                                     const float4& w3) {
  a.x = fmaf(v.x, w0.x, a.x); a.x = fmaf(v.y, w1.x, a.x);
  a.x = fmaf(v.z, w2.x, a.x); a.x = fmaf(v.w, w3.x, a.x);
  a.y = fmaf(v.x, w0.y, a.y); a.y = fmaf(v.y, w1.y, a.y);
  a.y = fmaf(v.z, w2.y, a.y); a.y = fmaf(v.w, w3.y, a.y);
  a.z = fmaf(v.x, w0.z, a.z); a.z = fmaf(v.y, w1.z, a.z);
  a.z = fmaf(v.z, w2.z, a.z); a.z = fmaf(v.w, w3.z, a.z);
  a.w = fmaf(v.x, w0.w, a.w); a.w = fmaf(v.y, w1.w, a.w);
  a.w = fmaf(v.z, w2.w, a.w); a.w = fmaf(v.w, w3.w, a.w);
}

// MIN: 0 = plain input load, 1 = apply BN(scale/shift)+relu while staging
// MOUT: 0 = +bias, 1 = relu(+bias), 2 = +bias and accumulate col sum/sumsq
template <int NOUT, int THREADS, int MIN, int MOUT>
__global__ __launch_bounds__(THREADS) void k_gemm(
    const float* __restrict__ in, const float* __restrict__ W,
    const float* __restrict__ bias, const float* __restrict__ gamma,
    const float* __restrict__ beta, float* __restrict__ csum,
    float* __restrict__ csq, float* __restrict__ out, int M) {
  constexpr int NC4 = NOUT / 4;        // float4 columns
  constexpr int RG = THREADS / NC4;    // row groups
  constexpr int TM = RG * 4;           // tile rows
  __shared__ float zs[TM * 128];       // input tile, row-major
  __shared__ float Ws[64 * NOUT];      // half-K of W
  const int tid = threadIdx.x;
  const int cq = tid % NC4;
  const int rg = tid / NC4;
  const int blockRow = blockIdx.x * TM;

  // BN params for this thread's staged k-quad (kq = tid%32 is constant across
  // staging iterations since THREADS % 32 == 0)
  const int kq_st = tid & 31;
  float sc[4], sh[4];
  if (MIN == 1) {
    float invM = 1.0f / (float)M;
#pragma unroll
    for (int j = 0; j < 4; ++j) {
      int k = kq_st * 4 + j;
      float mu = csum[k] * invM;
      float var = csq[k] * invM - mu * mu;
      float g = gamma[k] * rsqrtf(var + 1e-5f);
      sc[j] = g;
      sh[j] = fmaf(-mu, g, beta[k]);
    }
  }

  // stage input tile
  const float4* in4 = (const float4*)in;
  float4* zs4w = (float4*)zs;
#pragma unroll
  for (int i = 0; i < (TM * 32) / THREADS; ++i) {
    int f = tid + i * THREADS;
    int row = f >> 5;
    int kq = f & 31;
    int gr = blockRow + row;
    float4 v = make_float4(0.f, 0.f, 0.f, 0.f);
    if (gr < M) v = in4[(size_t)gr * 32 + kq];
    if (MIN == 1) {
      v.x = fmaxf(fmaf(v.x, sc[0], sh[0]), 0.f);
      v.y = fmaxf(fmaf(v.y, sc[1], sh[1]), 0.f);
      v.z = fmaxf(fmaf(v.z, sc[2], sh[2]), 0.f);
      v.w = fmaxf(fmaf(v.w, sc[3], sh[3]), 0.f);
    }
    zs4w[f] = v;
  }

  float4 acc[4];
#pragma unroll
  for (int r = 0; r < 4; ++r) acc[r] = make_float4(0.f, 0.f, 0.f, 0.f);

  const float4* zs4 = (const float4*)zs;
  const float4* Ws4 = (const float4*)Ws;
  const float4* Wg4 = (const float4*)W;

#pragma unroll
  for (int half = 0; half < 2; ++half) {
    __syncthreads();
#pragma unroll
    for (int i = 0; i < (64 * NC4) / THREADS; ++i) {
      int f = tid + i * THREADS;
      ((float4*)Ws)[f] = Wg4[(size_t)half * 64 * NC4 + f];
    }
    __syncthreads();
#pragma unroll
    for (int k4 = 0; k4 < 16; ++k4) {
      float4 a0 = zs4[(rg * 4 + 0) * 32 + half * 16 + k4];
      float4 a1 = zs4[(rg * 4 + 1) * 32 + half * 16 + k4];
      float4 a2 = zs4[(rg * 4 + 2) * 32 + half * 16 + k4];
      float4 a3 = zs4[(rg * 4 + 3) * 32 + half * 16 + k4];
      float4 w0 = Ws4[(k4 * 4 + 0) * NC4 + cq];
      float4 w1 = Ws4[(k4 * 4 + 1) * NC4 + cq];
      float4 w2 = Ws4[(k4 * 4 + 2) * NC4 + cq];
      float4 w3 = Ws4[(k4 * 4 + 3) * NC4 + cq];
      fma4(acc[0], a0, w0, w1, w2, w3);
      fma4(acc[1], a1, w0, w1, w2, w3);
      fma4(acc[2], a2, w0, w1, w2, w3);
      fma4(acc[3], a3, w0, w1, w2, w3);
    }
  }

  float4 bv = ((const float4*)bias)[cq];
#pragma unroll
  for (int r = 0; r < 4; ++r) {
    acc[r].x += bv.x; acc[r].y += bv.y; acc[r].z += bv.z; acc[r].w += bv.w;
    if (MOUT == 1) {
      acc[r].x = fmaxf(acc[r].x, 0.f); acc[r].y = fmaxf(acc[r].y, 0.f);
      acc[r].z = fmaxf(acc[r].z, 0.f); acc[r].w = fmaxf(acc[r].w, 0.f);
    }
  }

  float4* out4 = (float4*)out;
#pragma unroll
  for (int r = 0; r < 4; ++r) {
    int gr = blockRow + rg * 4 + r;
    if (gr < M) out4[(size_t)gr * NC4 + cq] = acc[r];
  }

  if (MOUT == 2) {
    // per-thread column partials over its (valid) 4 rows
    float ps[4] = {0, 0, 0, 0}, pq[4] = {0, 0, 0, 0};
#pragma unroll
    for (int r = 0; r < 4; ++r) {
      int gr = blockRow + rg * 4 + r;
      if (gr < M) {
        ps[0] += acc[r].x; pq[0] += acc[r].x * acc[r].x;
        ps[1] += acc[r].y; pq[1] += acc[r].y * acc[r].y;
        ps[2] += acc[r].z; pq[2] += acc[r].z * acc[r].z;
        ps[3] += acc[r].w; pq[3] += acc[r].w * acc[r].w;
      }
    }
    __syncthreads();  // done reading zs; reuse as reduction scratch
    float* sredS = zs;                 // [RG][NOUT]
    float* sredQ = zs + RG * NOUT;     // [RG][NOUT]
#pragma unroll
    for (int j = 0; j < 4; ++j) {
      sredS[rg * NOUT + cq * 4 + j] = ps[j];
      sredQ[rg * NOUT + cq * 4 + j] = pq[j];
    }
    __syncthreads();
    if (tid < NOUT) {
      float s = 0.f;
#pragma unroll
      for (int g = 0; g < RG; ++g) s += sredS[g * NOUT + tid];
      atomicAdd(&csum[tid], s);
    } else if (tid < 2 * NOUT) {
      int c = tid - NOUT;
      float q = 0.f;
#pragma unroll
      for (int g = 0; g < RG; ++g) q += sredQ[g * NOUT + c];
      atomicAdd(&csq[c], q);
    }
  }
}

// ---------------- launch ----------------

extern "C" void kernel_launch(void* const* d_in, const int* in_sizes, int n_in,
                              void* d_out, int out_size, void* d_ws, size_t ws_size,
                              hipStream_t stream) {
  const float* node_feat = (const float*)d_in[0];
  const int* src = (const int*)d_in[1];
  const int* dst = (const int*)d_in[2];
  const float* W1 = (const float*)d_in[3];
  const float* b1 = (const float*)d_in[4];
  const float* gamma = (const float*)d_in[5];
  const float* beta = (const float*)d_in[6];
  const float* W2 = (const float*)d_in[7];
  const float* b2 = (const float*)d_in[8];
  const float* eps = (const float*)d_in[9];
  const float* Wout = (const float*)d_in[10];
  const float* bout = (const float*)d_in[11];
  float* out = (float*)d_out;

  // workspace layout (16B-aligned slices)
  int* deg = (int*)d_ws;              // 50176 ints
  int* rs = deg + 50176;              // 50176 ints (uses 50001)
  int* cursor = rs + 50176;           // 50176 ints
  int* eidx = cursor + 50176;         // 1600000 ints
  float* zbuf = (float*)(eidx + NE);  // 6.4M floats
  float* hbuf = zbuf + (size_t)NN * HID;
  float* stats = hbuf + (size_t)NN * HID;  // 256 floats: csum|csq

  hipMemsetAsync(deg, 0, NN * sizeof(int), stream);
  k_hist<<<(NE + 255) / 256, 256, 0, stream>>>(dst, deg, NE);
  k_scan<<<1, 1024, 0, stream>>>(deg, rs, cursor, NN);
  k_scatter<<<(NE + 255) / 256, 256, 0, stream>>>(src, dst, cursor, eidx, NE);

  const int aggGrid = (NN * 64 + 255) / 256;   // one wave per node
  const int gemmGrid = (NN + 31) / 32;

  for (int L = 0; L < 3; ++L) {
    const float* hin = (L == 0) ? node_feat : hbuf;
    k_agg<<<aggGrid, 256, 0, stream>>>(hin, rs, eidx, eps, L, zbuf, NN);
    hipMemsetAsync(stats, 0, 256 * sizeof(float), stream);
    // x = z @ W1[L] + b1[L], in place, + column stats
    k_gemm<128, 256, 0, 2><<<gemmGrid, 256, 0, stream>>>(
        zbuf, W1 + (size_t)L * HID * HID, b1 + (size_t)L * HID, nullptr, nullptr,
        stats, stats + HID, zbuf, NN);
    // h = relu( relu(BN(x)) @ W2[L] + b2[L] )
    k_gemm<128, 256, 1, 1><<<gemmGrid, 256, 0, stream>>>(
        zbuf, W2 + (size_t)L * HID * HID, b2 + (size_t)L * HID,
        gamma + (size_t)L * HID, beta + (size_t)L * HID, stats, stats + HID, hbuf,
        NN);
  }
  // out = h @ Wout + bout
  k_gemm<64, 128, 0, 0><<<gemmGrid, 128, 0, stream>>>(
      hbuf, Wout, bout, nullptr, nullptr, nullptr, nullptr, out, NN);
}

// Round 3
// 1166.086 us; speedup vs baseline: 2.9316x; 2.9316x over previous
//
#include <hip/hip_runtime.h>

#define NN 50000
#define NE 1600000
#define HID 128

// ---------------- CSR build ----------------

__global__ __launch_bounds__(256) void k_hist(const int* __restrict__ dst,
                                              int* __restrict__ deg, int E) {
  int i = blockIdx.x * 256 + threadIdx.x;
  if (i < E) atomicAdd(&deg[dst[i]], 1);
}

__global__ __launch_bounds__(1024) void k_scan(const int* __restrict__ deg,
                                               int* __restrict__ rs,
                                               int* __restrict__ cursor, int M) {
  __shared__ int part[1024];
  int tid = threadIdx.x;
  int chunk = (M + 1023) >> 10;
  int lo = tid * chunk;
  int hi = min(lo + chunk, M);
  int s = 0;
  for (int i = lo; i < hi; ++i) s += deg[i];
  part[tid] = s;
  __syncthreads();
  int own = s;
  for (int d = 1; d < 1024; d <<= 1) {
    int t = (tid >= d) ? part[tid - d] : 0;
    __syncthreads();
    part[tid] += t;
    __syncthreads();
  }
  int run = part[tid] - own;  // exclusive prefix
  for (int i = lo; i < hi; ++i) {
    rs[i] = run;
    cursor[i] = run;
    run += deg[i];
  }
  if (tid == 1023) rs[M] = part[1023];
}

__global__ __launch_bounds__(256) void k_scatter(const int* __restrict__ src,
                                                 const int* __restrict__ dst,
                                                 int* __restrict__ cursor,
                                                 int* __restrict__ eidx, int E) {
  int i = blockIdx.x * 256 + threadIdx.x;
  if (i < E) {
    int d = dst[i];
    int p = atomicAdd(&cursor[d], 1);
    eidx[p] = src[i];
  }
}

// ---------------- aggregation: z = (1+eps)*h + sum_{e: dst=node} h[src_e] --------

__global__ __launch_bounds__(256) void k_agg(const float* __restrict__ h,
                                             const int* __restrict__ rs,
                                             const int* __restrict__ eidx,
                                             const float* __restrict__ eps, int layer,
                                             float* __restrict__ z, int M) {
  int node = (int)((blockIdx.x * 256 + threadIdx.x) >> 6);  // one wave per node
  int lane = threadIdx.x & 63;
  if (node >= M) return;
  float ep = 1.0f + eps[layer];
  const float2* h2 = (const float2*)h;
  int e0 = rs[node], e1 = rs[node + 1];
  float ax = 0.f, ay = 0.f;
  for (int e = e0; e < e1; ++e) {
    int s = eidx[e];
    float2 v = h2[(size_t)s * 64 + lane];
    ax += v.x;
    ay += v.y;
  }
  float2 hv = h2[(size_t)node * 64 + lane];
  float2 o;
  o.x = fmaf(ep, hv.x, ax);
  o.y = fmaf(ep, hv.y, ay);
  ((float2*)z)[(size_t)node * 64 + lane] = o;
}

// ---------------- row-wise GEMM (K=128), 64x64 tile, 4x4 per-thread acc ------
// MIN:  0 = plain input load, 1 = apply BN(scale/shift)+relu while staging
// MOUT: 0 = +bias, 1 = relu(+bias), 2 = +bias and accumulate col sum/sumsq
//
// NOTE: in/out must NOT alias — with column-split blocks (grid.y=2), two
// blocks read the same input rows; in-place operation races (round-2 bug).
// kernel_launch ping-pongs buffers so no GEMM is in-place.

#define APAD 132  // 128 + 4: keeps float4 alignment, breaks 32-bank stride

template <int NOUT, int MIN, int MOUT>
__global__ __launch_bounds__(256, 3) void k_gemm(
    const float* __restrict__ in, const float* __restrict__ W,
    const float* __restrict__ bias, const float* __restrict__ gamma,
    const float* __restrict__ beta, float* __restrict__ csum,
    float* __restrict__ csq, float* __restrict__ out, int M) {
  __shared__ float As[64 * APAD];  // 64 rows x 128 k (padded)
  __shared__ float Ws[64 * 64];    // 64 k x 64 cols (half-K staging)

  const int tid = threadIdx.x;
  const int cg = tid & 15;   // col group: cols colBase + cg*4 .. +3
  const int rg = tid >> 4;   // row group: rows rowBase + rg*4 .. +3 (0..15)
  const int rowBase = blockIdx.x * 64;
  const int colBase = blockIdx.y * 64;
  constexpr int NC4 = NOUT / 4;

  // BN params for this thread's staged k-quad (f & 31 == tid & 31 always)
  const int kq_st = tid & 31;
  float sc[4], sh[4];
  if (MIN == 1) {
    float invM = 1.0f / (float)M;
#pragma unroll
    for (int j = 0; j < 4; ++j) {
      int k = kq_st * 4 + j;
      float mu = csum[k] * invM;
      float var = csq[k] * invM - mu * mu;
      float g = gamma[k] * rsqrtf(var + 1e-5f);
      sc[j] = g;
      sh[j] = fmaf(-mu, g, beta[k]);
    }
  }

  // stage A tile (full K)
  const float4* in4 = (const float4*)in;
#pragma unroll
  for (int i = 0; i < 8; ++i) {
    int f = tid + i * 256;
    int row = f >> 5;
    int kq = f & 31;
    int gr = rowBase + row;
    float4 v = make_float4(0.f, 0.f, 0.f, 0.f);
    if (gr < M) v = in4[(size_t)gr * 32 + kq];
    if (MIN == 1) {
      v.x = fmaxf(fmaf(v.x, sc[0], sh[0]), 0.f);
      v.y = fmaxf(fmaf(v.y, sc[1], sh[1]), 0.f);
      v.z = fmaxf(fmaf(v.z, sc[2], sh[2]), 0.f);
      v.w = fmaxf(fmaf(v.w, sc[3], sh[3]), 0.f);
    }
    float* d = &As[row * APAD + kq * 4];
    d[0] = v.x; d[1] = v.y; d[2] = v.z; d[3] = v.w;
  }

  float4 acc[4];
#pragma unroll
  for (int r = 0; r < 4; ++r) acc[r] = make_float4(0.f, 0.f, 0.f, 0.f);

  const float4* Wg4 = (const float4*)W;
  const float4* Ws4 = (const float4*)Ws;

#pragma unroll
  for (int h = 0; h < 2; ++h) {
    // stage half-K of W: k in [h*64, h*64+64), cols [colBase, colBase+64)
#pragma unroll
    for (int i = 0; i < 4; ++i) {
      int f = tid + i * 256;
      int kk = f >> 4;
      int cq = f & 15;
      ((float4*)Ws)[kk * 16 + cq] =
          Wg4[(size_t)(h * 64 + kk) * NC4 + (colBase >> 2) + cq];
    }
    __syncthreads();  // covers A-stage (h=0) and W-stage

    const float* A0 = &As[(rg * 4 + 0) * APAD + h * 64];
    const float* A1 = &As[(rg * 4 + 1) * APAD + h * 64];
    const float* A2 = &As[(rg * 4 + 2) * APAD + h * 64];
    const float* A3 = &As[(rg * 4 + 3) * APAD + h * 64];

#pragma unroll 4
    for (int kk = 0; kk < 64; kk += 4) {
      float4 b0 = Ws4[(kk + 0) * 16 + cg];
      float4 b1 = Ws4[(kk + 1) * 16 + cg];
      float4 b2 = Ws4[(kk + 2) * 16 + cg];
      float4 b3 = Ws4[(kk + 3) * 16 + cg];
      float4 a0 = *(const float4*)(A0 + kk);
      float4 a1 = *(const float4*)(A1 + kk);
      float4 a2 = *(const float4*)(A2 + kk);
      float4 a3 = *(const float4*)(A3 + kk);
#define FMA_ROW(r, a)                                                       \
  acc[r].x = fmaf(a.x, b0.x, acc[r].x); acc[r].x = fmaf(a.y, b1.x, acc[r].x); \
  acc[r].x = fmaf(a.z, b2.x, acc[r].x); acc[r].x = fmaf(a.w, b3.x, acc[r].x); \
  acc[r].y = fmaf(a.x, b0.y, acc[r].y); acc[r].y = fmaf(a.y, b1.y, acc[r].y); \
  acc[r].y = fmaf(a.z, b2.y, acc[r].y); acc[r].y = fmaf(a.w, b3.y, acc[r].y); \
  acc[r].z = fmaf(a.x, b0.z, acc[r].z); acc[r].z = fmaf(a.y, b1.z, acc[r].z); \
  acc[r].z = fmaf(a.z, b2.z, acc[r].z); acc[r].z = fmaf(a.w, b3.z, acc[r].z); \
  acc[r].w = fmaf(a.x, b0.w, acc[r].w); acc[r].w = fmaf(a.y, b1.w, acc[r].w); \
  acc[r].w = fmaf(a.z, b2.w, acc[r].w); acc[r].w = fmaf(a.w, b3.w, acc[r].w);
      FMA_ROW(0, a0)
      FMA_ROW(1, a1)
      FMA_ROW(2, a2)
      FMA_ROW(3, a3)
#undef FMA_ROW
    }
    __syncthreads();  // protect Ws re-staging (and As scratch reuse below)
  }

  float4 bv = ((const float4*)bias)[(colBase >> 2) + cg];
#pragma unroll
  for (int r = 0; r < 4; ++r) {
    acc[r].x += bv.x; acc[r].y += bv.y; acc[r].z += bv.z; acc[r].w += bv.w;
    if (MOUT == 1) {
      acc[r].x = fmaxf(acc[r].x, 0.f); acc[r].y = fmaxf(acc[r].y, 0.f);
      acc[r].z = fmaxf(acc[r].z, 0.f); acc[r].w = fmaxf(acc[r].w, 0.f);
    }
  }

  float4* out4 = (float4*)out;
#pragma unroll
  for (int r = 0; r < 4; ++r) {
    int gr = rowBase + rg * 4 + r;
    if (gr < M) out4[(size_t)gr * NC4 + (colBase >> 2) + cg] = acc[r];
  }

  if (MOUT == 2) {
    // column partial sums over this thread's (valid) 4 rows
    float ps[4] = {0, 0, 0, 0}, pq[4] = {0, 0, 0, 0};
#pragma unroll
    for (int r = 0; r < 4; ++r) {
      int gr = rowBase + rg * 4 + r;
      if (gr < M) {
        ps[0] += acc[r].x; pq[0] += acc[r].x * acc[r].x;
        ps[1] += acc[r].y; pq[1] += acc[r].y * acc[r].y;
        ps[2] += acc[r].z; pq[2] += acc[r].z * acc[r].z;
        ps[3] += acc[r].w; pq[3] += acc[r].w * acc[r].w;
      }
    }
    float* sredS = As;          // [16 rg][64 cols]
    float* sredQ = As + 1024;   // [16 rg][64 cols]
#pragma unroll
    for (int j = 0; j < 4; ++j) {
      sredS[rg * 64 + cg * 4 + j] = ps[j];
      sredQ[rg * 64 + cg * 4 + j] = pq[j];
    }
    __syncthreads();
    if (tid < 64) {
      float s = 0.f;
#pragma unroll
      for (int g = 0; g < 16; ++g) s += sredS[g * 64 + tid];
      atomicAdd(&csum[colBase + tid], s);
    } else if (tid < 128) {
      int c = tid - 64;
      float q = 0.f;
#pragma unroll
      for (int g = 0; g < 16; ++g) q += sredQ[g * 64 + c];
      atomicAdd(&csq[colBase + c], q);
    }
  }
}

// ---------------- launch ----------------

extern "C" void kernel_launch(void* const* d_in, const int* in_sizes, int n_in,
                              void* d_out, int out_size, void* d_ws, size_t ws_size,
                              hipStream_t stream) {
  const float* node_feat = (const float*)d_in[0];
  const int* src = (const int*)d_in[1];
  const int* dst = (const int*)d_in[2];
  const float* W1 = (const float*)d_in[3];
  const float* b1 = (const float*)d_in[4];
  const float* gamma = (const float*)d_in[5];
  const float* beta = (const float*)d_in[6];
  const float* W2 = (const float*)d_in[7];
  const float* b2 = (const float*)d_in[8];
  const float* eps = (const float*)d_in[9];
  const float* Wout = (const float*)d_in[10];
  const float* bout = (const float*)d_in[11];
  float* out = (float*)d_out;

  // workspace layout (16B-aligned slices)
  int* deg = (int*)d_ws;              // 50176 ints
  int* rs = deg + 50176;              // 50176 ints (uses 50001)
  int* cursor = rs + 50176;           // 50176 ints
  int* eidx = cursor + 50176;         // 1600000 ints
  float* zbuf = (float*)(eidx + NE);  // 6.4M floats
  float* hbuf = zbuf + (size_t)NN * HID;
  float* stats = hbuf + (size_t)NN * HID;  // 256 floats: csum|csq

  hipMemsetAsync(deg, 0, NN * sizeof(int), stream);
  k_hist<<<(NE + 255) / 256, 256, 0, stream>>>(dst, deg, NE);
  k_scan<<<1, 1024, 0, stream>>>(deg, rs, cursor, NN);
  k_scatter<<<(NE + 255) / 256, 256, 0, stream>>>(src, dst, cursor, eidx, NE);

  const int aggGrid = (NN * 64 + 255) / 256;  // one wave per node
  const int rowTiles = (NN + 63) / 64;        // 782

  // Ping-pong: per layer, z and h' live in one buffer, x in the other.
  //   agg:   hcur -> zb      GEMM1: zb -> xb      GEMM2: xb -> zb
  const float* hcur = node_feat;
  for (int L = 0; L < 3; ++L) {
    float* zb = (L & 1) ? hbuf : zbuf;
    float* xb = (L & 1) ? zbuf : hbuf;
    k_agg<<<aggGrid, 256, 0, stream>>>(hcur, rs, eidx, eps, L, zb, NN);
    hipMemsetAsync(stats, 0, 256 * sizeof(float), stream);
    // x = z @ W1[L] + b1[L], + column stats
    k_gemm<128, 0, 2><<<dim3(rowTiles, 2), 256, 0, stream>>>(
        zb, W1 + (size_t)L * HID * HID, b1 + (size_t)L * HID, nullptr, nullptr,
        stats, stats + HID, xb, NN);
    // h' = relu( relu(BN(x)) @ W2[L] + b2[L] )
    k_gemm<128, 1, 1><<<dim3(rowTiles, 2), 256, 0, stream>>>(
        xb, W2 + (size_t)L * HID * HID, b2 + (size_t)L * HID,
        gamma + (size_t)L * HID, beta + (size_t)L * HID, stats, stats + HID, zb,
        NN);
    hcur = zb;
  }
  // out = h @ Wout + bout   (hcur == zbuf after 3 layers)
  k_gemm<64, 0, 0><<<dim3(rowTiles, 1), 256, 0, stream>>>(
      hcur, Wout, bout, nullptr, nullptr, nullptr, nullptr, out, NN);
}

// Round 4
// 1004.315 us; speedup vs baseline: 3.4038x; 1.1611x over previous
//
#include <hip/hip_runtime.h>

#define NN 50000
#define NE 1600000
#define HID 128

// ---------------- CSR build ----------------

__global__ __launch_bounds__(256) void k_hist(const int* __restrict__ dst,
                                              int* __restrict__ deg, int E) {
  int i = blockIdx.x * 256 + threadIdx.x;
  if (i < E) atomicAdd(&deg[dst[i]], 1);
}

__global__ __launch_bounds__(1024) void k_scan(const int* __restrict__ deg,
                                               int* __restrict__ rs,
                                               int* __restrict__ cursor, int M) {
  __shared__ int part[1024];
  int tid = threadIdx.x;
  int chunk = (M + 1023) >> 10;
  int lo = tid * chunk;
  int hi = min(lo + chunk, M);
  int s = 0;
  for (int i = lo; i < hi; ++i) s += deg[i];
  part[tid] = s;
  __syncthreads();
  int own = s;
  for (int d = 1; d < 1024; d <<= 1) {
    int t = (tid >= d) ? part[tid - d] : 0;
    __syncthreads();
    part[tid] += t;
    __syncthreads();
  }
  int run = part[tid] - own;  // exclusive prefix
  for (int i = lo; i < hi; ++i) {
    rs[i] = run;
    cursor[i] = run;
    run += deg[i];
  }
  if (tid == 1023) rs[M] = part[1023];
}

__global__ __launch_bounds__(256) void k_scatter(const int* __restrict__ src,
                                                 const int* __restrict__ dst,
                                                 int* __restrict__ cursor,
                                                 int* __restrict__ eidx, int E) {
  int i = blockIdx.x * 256 + threadIdx.x;
  if (i < E) {
    int d = dst[i];
    int p = atomicAdd(&cursor[d], 1);
    eidx[p] = src[i];
  }
}

// ---------------- aggregation: z = (1+eps)*h + sum_{e: dst=node} h[src_e] --------
// One wave per node. float4 per lane, 32 lanes per 128-float row, so the wave
// covers 2 edges per load instruction (half = lane>>5 picks the edge).
// 8-edge unroll (4 per half) with 4 independent accumulators: round-3 version
// compiled to 8 VGPRs / 1 outstanding load and was pure latency-bound.

__global__ __launch_bounds__(256) void k_agg(const float* __restrict__ h,
                                             const int* __restrict__ rs,
                                             const int* __restrict__ eidx,
                                             const float* __restrict__ eps, int layer,
                                             float* __restrict__ z, int M) {
  int node = (int)((blockIdx.x * 256 + threadIdx.x) >> 6);
  if (node >= M) return;
  const int lane = threadIdx.x & 63;
  const int half = lane >> 5;  // which edge of the pair
  const int col = lane & 31;   // float4 column within the row

  const float4* h4 = (const float4*)h;
  int e0 = rs[node], e1 = rs[node + 1];

  float4 a0 = make_float4(0.f, 0.f, 0.f, 0.f);
  float4 a1 = make_float4(0.f, 0.f, 0.f, 0.f);
  float4 a2 = make_float4(0.f, 0.f, 0.f, 0.f);
  float4 a3 = make_float4(0.f, 0.f, 0.f, 0.f);

#define ACC4(A, V) \
  A.x += V.x; A.y += V.y; A.z += V.z; A.w += V.w;

  int e = e0 + half;
  for (; e + 6 < e1; e += 8) {
    int s0 = eidx[e];
    int s1 = eidx[e + 2];
    int s2 = eidx[e + 4];
    int s3 = eidx[e + 6];
    float4 v0 = h4[(size_t)s0 * 32 + col];
    float4 v1 = h4[(size_t)s1 * 32 + col];
    float4 v2 = h4[(size_t)s2 * 32 + col];
    float4 v3 = h4[(size_t)s3 * 32 + col];
    ACC4(a0, v0)
    ACC4(a1, v1)
    ACC4(a2, v2)
    ACC4(a3, v3)
  }
  for (; e < e1; e += 2) {
    int s = eidx[e];
    float4 v = h4[(size_t)s * 32 + col];
    ACC4(a0, v)
  }
#undef ACC4

  a0.x += a1.x + a2.x + a3.x;
  a0.y += a1.y + a2.y + a3.y;
  a0.z += a1.z + a2.z + a3.z;
  a0.w += a1.w + a2.w + a3.w;

  // combine the two half-wave partials
  a0.x += __shfl_xor(a0.x, 32);
  a0.y += __shfl_xor(a0.y, 32);
  a0.z += __shfl_xor(a0.z, 32);
  a0.w += __shfl_xor(a0.w, 32);

  if (half == 0) {
    float ep = 1.0f + eps[layer];
    float4 hv = h4[(size_t)node * 32 + col];
    float4 o;
    o.x = fmaf(ep, hv.x, a0.x);
    o.y = fmaf(ep, hv.y, a0.y);
    o.z = fmaf(ep, hv.z, a0.z);
    o.w = fmaf(ep, hv.w, a0.w);
    ((float4*)z)[(size_t)node * 32 + col] = o;
  }
}

// ---------------- row-wise GEMM (K=128), 64x64 tile, 4x4 per-thread acc ------
// MIN:  0 = plain input load, 1 = apply BN(scale/shift)+relu while staging
// MOUT: 0 = +bias, 1 = relu(+bias), 2 = +bias and accumulate col sum/sumsq
//
// NOTE: in/out must NOT alias — with column-split blocks (grid.y=2), two
// blocks read the same input rows; in-place operation races (round-2 bug).
// kernel_launch ping-pongs buffers so no GEMM is in-place.

#define APAD 132  // 128 + 4: keeps float4 alignment, breaks 32-bank stride

template <int NOUT, int MIN, int MOUT>
__global__ __launch_bounds__(256, 3) void k_gemm(
    const float* __restrict__ in, const float* __restrict__ W,
    const float* __restrict__ bias, const float* __restrict__ gamma,
    const float* __restrict__ beta, float* __restrict__ csum,
    float* __restrict__ csq, float* __restrict__ out, int M) {
  __shared__ float As[64 * APAD];  // 64 rows x 128 k (padded)
  __shared__ float Ws[64 * 64];    // 64 k x 64 cols (half-K staging)

  const int tid = threadIdx.x;
  const int cg = tid & 15;   // col group: cols colBase + cg*4 .. +3
  const int rg = tid >> 4;   // row group: rows rowBase + rg*4 .. +3 (0..15)
  const int rowBase = blockIdx.x * 64;
  const int colBase = blockIdx.y * 64;
  constexpr int NC4 = NOUT / 4;

  // BN params for this thread's staged k-quad (f & 31 == tid & 31 always)
  const int kq_st = tid & 31;
  float sc[4], sh[4];
  if (MIN == 1) {
    float invM = 1.0f / (float)M;
#pragma unroll
    for (int j = 0; j < 4; ++j) {
      int k = kq_st * 4 + j;
      float mu = csum[k] * invM;
      float var = csq[k] * invM - mu * mu;
      float g = gamma[k] * rsqrtf(var + 1e-5f);
      sc[j] = g;
      sh[j] = fmaf(-mu, g, beta[k]);
    }
  }

  // stage A tile (full K)
  const float4* in4 = (const float4*)in;
#pragma unroll
  for (int i = 0; i < 8; ++i) {
    int f = tid + i * 256;
    int row = f >> 5;
    int kq = f & 31;
    int gr = rowBase + row;
    float4 v = make_float4(0.f, 0.f, 0.f, 0.f);
    if (gr < M) v = in4[(size_t)gr * 32 + kq];
    if (MIN == 1) {
      v.x = fmaxf(fmaf(v.x, sc[0], sh[0]), 0.f);
      v.y = fmaxf(fmaf(v.y, sc[1], sh[1]), 0.f);
      v.z = fmaxf(fmaf(v.z, sc[2], sh[2]), 0.f);
      v.w = fmaxf(fmaf(v.w, sc[3], sh[3]), 0.f);
    }
    float* d = &As[row * APAD + kq * 4];
    d[0] = v.x; d[1] = v.y; d[2] = v.z; d[3] = v.w;
  }

  float4 acc[4];
#pragma unroll
  for (int r = 0; r < 4; ++r) acc[r] = make_float4(0.f, 0.f, 0.f, 0.f);

  const float4* Wg4 = (const float4*)W;
  const float4* Ws4 = (const float4*)Ws;

#pragma unroll
  for (int h = 0; h < 2; ++h) {
    // stage half-K of W: k in [h*64, h*64+64), cols [colBase, colBase+64)
#pragma unroll
    for (int i = 0; i < 4; ++i) {
      int f = tid + i * 256;
      int kk = f >> 4;
      int cq = f & 15;
      ((float4*)Ws)[kk * 16 + cq] =
          Wg4[(size_t)(h * 64 + kk) * NC4 + (colBase >> 2) + cq];
    }
    __syncthreads();  // covers A-stage (h=0) and W-stage

    const float* A0 = &As[(rg * 4 + 0) * APAD + h * 64];
    const float* A1 = &As[(rg * 4 + 1) * APAD + h * 64];
    const float* A2 = &As[(rg * 4 + 2) * APAD + h * 64];
    const float* A3 = &As[(rg * 4 + 3) * APAD + h * 64];

#pragma unroll 4
    for (int kk = 0; kk < 64; kk += 4) {
      float4 b0 = Ws4[(kk + 0) * 16 + cg];
      float4 b1 = Ws4[(kk + 1) * 16 + cg];
      float4 b2 = Ws4[(kk + 2) * 16 + cg];
      float4 b3 = Ws4[(kk + 3) * 16 + cg];
      float4 a0 = *(const float4*)(A0 + kk);
      float4 a1 = *(const float4*)(A1 + kk);
      float4 a2 = *(const float4*)(A2 + kk);
      float4 a3 = *(const float4*)(A3 + kk);
#define FMA_ROW(r, a)                                                       \
  acc[r].x = fmaf(a.x, b0.x, acc[r].x); acc[r].x = fmaf(a.y, b1.x, acc[r].x); \
  acc[r].x = fmaf(a.z, b2.x, acc[r].x); acc[r].x = fmaf(a.w, b3.x, acc[r].x); \
  acc[r].y = fmaf(a.x, b0.y, acc[r].y); acc[r].y = fmaf(a.y, b1.y, acc[r].y); \
  acc[r].y = fmaf(a.z, b2.y, acc[r].y); acc[r].y = fmaf(a.w, b3.y, acc[r].y); \
  acc[r].z = fmaf(a.x, b0.z, acc[r].z); acc[r].z = fmaf(a.y, b1.z, acc[r].z); \
  acc[r].z = fmaf(a.z, b2.z, acc[r].z); acc[r].z = fmaf(a.w, b3.z, acc[r].z); \
  acc[r].w = fmaf(a.x, b0.w, acc[r].w); acc[r].w = fmaf(a.y, b1.w, acc[r].w); \
  acc[r].w = fmaf(a.z, b2.w, acc[r].w); acc[r].w = fmaf(a.w, b3.w, acc[r].w);
      FMA_ROW(0, a0)
      FMA_ROW(1, a1)
      FMA_ROW(2, a2)
      FMA_ROW(3, a3)
#undef FMA_ROW
    }
    __syncthreads();  // protect Ws re-staging (and As scratch reuse below)
  }

  float4 bv = ((const float4*)bias)[(colBase >> 2) + cg];
#pragma unroll
  for (int r = 0; r < 4; ++r) {
    acc[r].x += bv.x; acc[r].y += bv.y; acc[r].z += bv.z; acc[r].w += bv.w;
    if (MOUT == 1) {
      acc[r].x = fmaxf(acc[r].x, 0.f); acc[r].y = fmaxf(acc[r].y, 0.f);
      acc[r].z = fmaxf(acc[r].z, 0.f); acc[r].w = fmaxf(acc[r].w, 0.f);
    }
  }

  float4* out4 = (float4*)out;
#pragma unroll
  for (int r = 0; r < 4; ++r) {
    int gr = rowBase + rg * 4 + r;
    if (gr < M) out4[(size_t)gr * NC4 + (colBase >> 2) + cg] = acc[r];
  }

  if (MOUT == 2) {
    // column partial sums over this thread's (valid) 4 rows
    float ps[4] = {0, 0, 0, 0}, pq[4] = {0, 0, 0, 0};
#pragma unroll
    for (int r = 0; r < 4; ++r) {
      int gr = rowBase + rg * 4 + r;
      if (gr < M) {
        ps[0] += acc[r].x; pq[0] += acc[r].x * acc[r].x;
        ps[1] += acc[r].y; pq[1] += acc[r].y * acc[r].y;
        ps[2] += acc[r].z; pq[2] += acc[r].z * acc[r].z;
        ps[3] += acc[r].w; pq[3] += acc[r].w * acc[r].w;
      }
    }
    float* sredS = As;          // [16 rg][64 cols]
    float* sredQ = As + 1024;   // [16 rg][64 cols]
#pragma unroll
    for (int j = 0; j < 4; ++j) {
      sredS[rg * 64 + cg * 4 + j] = ps[j];
      sredQ[rg * 64 + cg * 4 + j] = pq[j];
    }
    __syncthreads();
    if (tid < 64) {
      float s = 0.f;
#pragma unroll
      for (int g = 0; g < 16; ++g) s += sredS[g * 64 + tid];
      atomicAdd(&csum[colBase + tid], s);
    } else if (tid < 128) {
      int c = tid - 64;
      float q = 0.f;
#pragma unroll
      for (int g = 0; g < 16; ++g) q += sredQ[g * 64 + c];
      atomicAdd(&csq[colBase + c], q);
    }
  }
}

// ---------------- launch ----------------

extern "C" void kernel_launch(void* const* d_in, const int* in_sizes, int n_in,
                              void* d_out, int out_size, void* d_ws, size_t ws_size,
                              hipStream_t stream) {
  const float* node_feat = (const float*)d_in[0];
  const int* src = (const int*)d_in[1];
  const int* dst = (const int*)d_in[2];
  const float* W1 = (const float*)d_in[3];
  const float* b1 = (const float*)d_in[4];
  const float* gamma = (const float*)d_in[5];
  const float* beta = (const float*)d_in[6];
  const float* W2 = (const float*)d_in[7];
  const float* b2 = (const float*)d_in[8];
  const float* eps = (const float*)d_in[9];
  const float* Wout = (const float*)d_in[10];
  const float* bout = (const float*)d_in[11];
  float* out = (float*)d_out;

  // workspace layout (16B-aligned slices)
  int* deg = (int*)d_ws;              // 50176 ints
  int* rs = deg + 50176;              // 50176 ints (uses 50001)
  int* cursor = rs + 50176;           // 50176 ints
  int* eidx = cursor + 50176;         // 1600000 ints
  float* zbuf = (float*)(eidx + NE);  // 6.4M floats
  float* hbuf = zbuf + (size_t)NN * HID;
  float* stats = hbuf + (size_t)NN * HID;  // 256 floats: csum|csq

  hipMemsetAsync(deg, 0, NN * sizeof(int), stream);
  k_hist<<<(NE + 255) / 256, 256, 0, stream>>>(dst, deg, NE);
  k_scan<<<1, 1024, 0, stream>>>(deg, rs, cursor, NN);
  k_scatter<<<(NE + 255) / 256, 256, 0, stream>>>(src, dst, cursor, eidx, NE);

  const int aggGrid = (NN * 64 + 255) / 256;  // one wave per node
  const int rowTiles = (NN + 63) / 64;        // 782

  // Ping-pong: per layer, z and h' live in one buffer, x in the other.
  //   agg:   hcur -> zb      GEMM1: zb -> xb      GEMM2: xb -> zb
  const float* hcur = node_feat;
  for (int L = 0; L < 3; ++L) {
    float* zb = (L & 1) ? hbuf : zbuf;
    float* xb = (L & 1) ? zbuf : hbuf;
    k_agg<<<aggGrid, 256, 0, stream>>>(hcur, rs, eidx, eps, L, zb, NN);
    hipMemsetAsync(stats, 0, 256 * sizeof(float), stream);
    // x = z @ W1[L] + b1[L], + column stats
    k_gemm<128, 0, 2><<<dim3(rowTiles, 2), 256, 0, stream>>>(
        zb, W1 + (size_t)L * HID * HID, b1 + (size_t)L * HID, nullptr, nullptr,
        stats, stats + HID, xb, NN);
    // h' = relu( relu(BN(x)) @ W2[L] + b2[L] )
    k_gemm<128, 1, 1><<<dim3(rowTiles, 2), 256, 0, stream>>>(
        xb, W2 + (size_t)L * HID * HID, b2 + (size_t)L * HID,
        gamma + (size_t)L * HID, beta + (size_t)L * HID, stats, stats + HID, zb,
        NN);
    hcur = zb;
  }
  // out = h @ Wout + bout   (hcur == zbuf after 3 layers)
  k_gemm<64, 0, 0><<<dim3(rowTiles, 1), 256, 0, stream>>>(
      hcur, Wout, bout, nullptr, nullptr, nullptr, nullptr, out, NN);
}

// Round 5
// 992.850 us; speedup vs baseline: 3.4431x; 1.0115x over previous
//
#include <hip/hip_runtime.h>

#define NN 50000
#define NE 1600000
#define HID 128

// ---------------- CSR build ----------------
// 8 edges per thread: the scatter's per-edge chain (load dst -> atomicAdd
// returning position -> scattered store) is pure latency; round-4 profile
// showed VGPR=4 / MLP=1 / 134 us. Unrolling gives 8 independent chains.

__global__ __launch_bounds__(256) void k_hist(const int* __restrict__ dst,
                                              int* __restrict__ deg, int E) {
  int t = blockIdx.x * 256 + threadIdx.x;
  int base = t * 8;
  if (base + 8 <= E) {
    int4 d0 = *(const int4*)(dst + base);
    int4 d1 = *(const int4*)(dst + base + 4);
    atomicAdd(&deg[d0.x], 1);
    atomicAdd(&deg[d0.y], 1);
    atomicAdd(&deg[d0.z], 1);
    atomicAdd(&deg[d0.w], 1);
    atomicAdd(&deg[d1.x], 1);
    atomicAdd(&deg[d1.y], 1);
    atomicAdd(&deg[d1.z], 1);
    atomicAdd(&deg[d1.w], 1);
  } else {
    for (int i = base; i < E; ++i) atomicAdd(&deg[dst[i]], 1);
  }
}

__global__ __launch_bounds__(1024) void k_scan(const int* __restrict__ deg,
                                               int* __restrict__ rs,
                                               int* __restrict__ cursor, int M) {
  __shared__ int part[1024];
  int tid = threadIdx.x;
  int chunk = (M + 1023) >> 10;
  int lo = tid * chunk;
  int hi = min(lo + chunk, M);
  int s = 0;
  for (int i = lo; i < hi; ++i) s += deg[i];
  part[tid] = s;
  __syncthreads();
  int own = s;
  for (int d = 1; d < 1024; d <<= 1) {
    int t = (tid >= d) ? part[tid - d] : 0;
    __syncthreads();
    part[tid] += t;
    __syncthreads();
  }
  int run = part[tid] - own;  // exclusive prefix
  for (int i = lo; i < hi; ++i) {
    rs[i] = run;
    cursor[i] = run;
    run += deg[i];
  }
  if (tid == 1023) rs[M] = part[1023];
}

__global__ __launch_bounds__(256) void k_scatter(const int* __restrict__ src,
                                                 const int* __restrict__ dst,
                                                 int* __restrict__ cursor,
                                                 int* __restrict__ eidx, int E) {
  int t = blockIdx.x * 256 + threadIdx.x;
  int base = t * 8;
  if (base + 8 <= E) {
    int4 s0 = *(const int4*)(src + base);
    int4 s1 = *(const int4*)(src + base + 4);
    int4 d0 = *(const int4*)(dst + base);
    int4 d1 = *(const int4*)(dst + base + 4);
    // 8 independent atomics in flight, then 8 independent stores
    int p0 = atomicAdd(&cursor[d0.x], 1);
    int p1 = atomicAdd(&cursor[d0.y], 1);
    int p2 = atomicAdd(&cursor[d0.z], 1);
    int p3 = atomicAdd(&cursor[d0.w], 1);
    int p4 = atomicAdd(&cursor[d1.x], 1);
    int p5 = atomicAdd(&cursor[d1.y], 1);
    int p6 = atomicAdd(&cursor[d1.z], 1);
    int p7 = atomicAdd(&cursor[d1.w], 1);
    eidx[p0] = s0.x;
    eidx[p1] = s0.y;
    eidx[p2] = s0.z;
    eidx[p3] = s0.w;
    eidx[p4] = s1.x;
    eidx[p5] = s1.y;
    eidx[p6] = s1.z;
    eidx[p7] = s1.w;
  } else {
    for (int i = base; i < E; ++i) {
      int p = atomicAdd(&cursor[dst[i]], 1);
      eidx[p] = src[i];
    }
  }
}

// ---------------- aggregation: z = (1+eps)*h + sum_{e: dst=node} h[src_e] --------
// One wave per node. float4 per lane, 32 lanes per 128-float row, so the wave
// covers 2 edges per load instruction (half = lane>>5 picks the edge).
// 8-edge unroll (4 per half) with 4 independent accumulators.

__global__ __launch_bounds__(256) void k_agg(const float* __restrict__ h,
                                             const int* __restrict__ rs,
                                             const int* __restrict__ eidx,
                                             const float* __restrict__ eps, int layer,
                                             float* __restrict__ z, int M) {
  int node = (int)((blockIdx.x * 256 + threadIdx.x) >> 6);
  if (node >= M) return;
  const int lane = threadIdx.x & 63;
  const int half = lane >> 5;  // which edge of the pair
  const int col = lane & 31;   // float4 column within the row

  const float4* h4 = (const float4*)h;
  int e0 = rs[node], e1 = rs[node + 1];

  float4 a0 = make_float4(0.f, 0.f, 0.f, 0.f);
  float4 a1 = make_float4(0.f, 0.f, 0.f, 0.f);
  float4 a2 = make_float4(0.f, 0.f, 0.f, 0.f);
  float4 a3 = make_float4(0.f, 0.f, 0.f, 0.f);

#define ACC4(A, V) \
  A.x += V.x; A.y += V.y; A.z += V.z; A.w += V.w;

  int e = e0 + half;
  for (; e + 6 < e1; e += 8) {
    int s0 = eidx[e];
    int s1 = eidx[e + 2];
    int s2 = eidx[e + 4];
    int s3 = eidx[e + 6];
    float4 v0 = h4[(size_t)s0 * 32 + col];
    float4 v1 = h4[(size_t)s1 * 32 + col];
    float4 v2 = h4[(size_t)s2 * 32 + col];
    float4 v3 = h4[(size_t)s3 * 32 + col];
    ACC4(a0, v0)
    ACC4(a1, v1)
    ACC4(a2, v2)
    ACC4(a3, v3)
  }
  for (; e < e1; e += 2) {
    int s = eidx[e];
    float4 v = h4[(size_t)s * 32 + col];
    ACC4(a0, v)
  }
#undef ACC4

  a0.x += a1.x + a2.x + a3.x;
  a0.y += a1.y + a2.y + a3.y;
  a0.z += a1.z + a2.z + a3.z;
  a0.w += a1.w + a2.w + a3.w;

  // combine the two half-wave partials
  a0.x += __shfl_xor(a0.x, 32);
  a0.y += __shfl_xor(a0.y, 32);
  a0.z += __shfl_xor(a0.z, 32);
  a0.w += __shfl_xor(a0.w, 32);

  if (half == 0) {
    float ep = 1.0f + eps[layer];
    float4 hv = h4[(size_t)node * 32 + col];
    float4 o;
    o.x = fmaf(ep, hv.x, a0.x);
    o.y = fmaf(ep, hv.y, a0.y);
    o.z = fmaf(ep, hv.z, a0.z);
    o.w = fmaf(ep, hv.w, a0.w);
    ((float4*)z)[(size_t)node * 32 + col] = o;
  }
}

// ---------------- row-wise GEMM (K=128), 64x64 tile, 4x4 per-thread acc ------
// MIN:  0 = plain input load, 1 = apply BN(scale/shift)+relu while staging
// MOUT: 0 = +bias, 1 = relu(+bias), 2 = +bias and accumulate col sum/sumsq
//
// NOTE: in/out must NOT alias — with column-split blocks (grid.y=2), two
// blocks read the same input rows; in-place operation races (round-2 bug).
// kernel_launch ping-pongs buffers so no GEMM is in-place.

#define APAD 132  // 128 + 4: keeps float4 alignment, breaks 32-bank stride

template <int NOUT, int MIN, int MOUT>
__global__ __launch_bounds__(256, 3) void k_gemm(
    const float* __restrict__ in, const float* __restrict__ W,
    const float* __restrict__ bias, const float* __restrict__ gamma,
    const float* __restrict__ beta, float* __restrict__ csum,
    float* __restrict__ csq, float* __restrict__ out, int M) {
  __shared__ float As[64 * APAD];  // 64 rows x 128 k (padded)
  __shared__ float Ws[64 * 64];    // 64 k x 64 cols (half-K staging)

  const int tid = threadIdx.x;
  const int cg = tid & 15;   // col group: cols colBase + cg*4 .. +3
  const int rg = tid >> 4;   // row group: rows rowBase + rg*4 .. +3 (0..15)
  const int rowBase = blockIdx.x * 64;
  const int colBase = blockIdx.y * 64;
  constexpr int NC4 = NOUT / 4;

  // BN params for this thread's staged k-quad (f & 31 == tid & 31 always)
  const int kq_st = tid & 31;
  float sc[4], sh[4];
  if (MIN == 1) {
    float invM = 1.0f / (float)M;
#pragma unroll
    for (int j = 0; j < 4; ++j) {
      int k = kq_st * 4 + j;
      float mu = csum[k] * invM;
      float var = csq[k] * invM - mu * mu;
      float g = gamma[k] * rsqrtf(var + 1e-5f);
      sc[j] = g;
      sh[j] = fmaf(-mu, g, beta[k]);
    }
  }

  // stage A tile (full K)
  const float4* in4 = (const float4*)in;
#pragma unroll
  for (int i = 0; i < 8; ++i) {
    int f = tid + i * 256;
    int row = f >> 5;
    int kq = f & 31;
    int gr = rowBase + row;
    float4 v = make_float4(0.f, 0.f, 0.f, 0.f);
    if (gr < M) v = in4[(size_t)gr * 32 + kq];
    if (MIN == 1) {
      v.x = fmaxf(fmaf(v.x, sc[0], sh[0]), 0.f);
      v.y = fmaxf(fmaf(v.y, sc[1], sh[1]), 0.f);
      v.z = fmaxf(fmaf(v.z, sc[2], sh[2]), 0.f);
      v.w = fmaxf(fmaf(v.w, sc[3], sh[3]), 0.f);
    }
    float* d = &As[row * APAD + kq * 4];
    d[0] = v.x; d[1] = v.y; d[2] = v.z; d[3] = v.w;
  }

  float4 acc[4];
#pragma unroll
  for (int r = 0; r < 4; ++r) acc[r] = make_float4(0.f, 0.f, 0.f, 0.f);

  const float4* Wg4 = (const float4*)W;
  const float4* Ws4 = (const float4*)Ws;

#pragma unroll
  for (int h = 0; h < 2; ++h) {
    // stage half-K of W: k in [h*64, h*64+64), cols [colBase, colBase+64)
#pragma unroll
    for (int i = 0; i < 4; ++i) {
      int f = tid + i * 256;
      int kk = f >> 4;
      int cq = f & 15;
      ((float4*)Ws)[kk * 16 + cq] =
          Wg4[(size_t)(h * 64 + kk) * NC4 + (colBase >> 2) + cq];
    }
    __syncthreads();  // covers A-stage (h=0) and W-stage

    const float* A0 = &As[(rg * 4 + 0) * APAD + h * 64];
    const float* A1 = &As[(rg * 4 + 1) * APAD + h * 64];
    const float* A2 = &As[(rg * 4 + 2) * APAD + h * 64];
    const float* A3 = &As[(rg * 4 + 3) * APAD + h * 64];

#pragma unroll 4
    for (int kk = 0; kk < 64; kk += 4) {
      float4 b0 = Ws4[(kk + 0) * 16 + cg];
      float4 b1 = Ws4[(kk + 1) * 16 + cg];
      float4 b2 = Ws4[(kk + 2) * 16 + cg];
      float4 b3 = Ws4[(kk + 3) * 16 + cg];
      float4 a0 = *(const float4*)(A0 + kk);
      float4 a1 = *(const float4*)(A1 + kk);
      float4 a2 = *(const float4*)(A2 + kk);
      float4 a3 = *(const float4*)(A3 + kk);
#define FMA_ROW(r, a)                                                       \
  acc[r].x = fmaf(a.x, b0.x, acc[r].x); acc[r].x = fmaf(a.y, b1.x, acc[r].x); \
  acc[r].x = fmaf(a.z, b2.x, acc[r].x); acc[r].x = fmaf(a.w, b3.x, acc[r].x); \
  acc[r].y = fmaf(a.x, b0.y, acc[r].y); acc[r].y = fmaf(a.y, b1.y, acc[r].y); \
  acc[r].y = fmaf(a.z, b2.y, acc[r].y); acc[r].y = fmaf(a.w, b3.y, acc[r].y); \
  acc[r].z = fmaf(a.x, b0.z, acc[r].z); acc[r].z = fmaf(a.y, b1.z, acc[r].z); \
  acc[r].z = fmaf(a.z, b2.z, acc[r].z); acc[r].z = fmaf(a.w, b3.z, acc[r].z); \
  acc[r].w = fmaf(a.x, b0.w, acc[r].w); acc[r].w = fmaf(a.y, b1.w, acc[r].w); \
  acc[r].w = fmaf(a.z, b2.w, acc[r].w); acc[r].w = fmaf(a.w, b3.w, acc[r].w);
      FMA_ROW(0, a0)
      FMA_ROW(1, a1)
      FMA_ROW(2, a2)
      FMA_ROW(3, a3)
#undef FMA_ROW
    }
    __syncthreads();  // protect Ws re-staging (and As scratch reuse below)
  }

  float4 bv = ((const float4*)bias)[(colBase >> 2) + cg];
#pragma unroll
  for (int r = 0; r < 4; ++r) {
    acc[r].x += bv.x; acc[r].y += bv.y; acc[r].z += bv.z; acc[r].w += bv.w;
    if (MOUT == 1) {
      acc[r].x = fmaxf(acc[r].x, 0.f); acc[r].y = fmaxf(acc[r].y, 0.f);
      acc[r].z = fmaxf(acc[r].z, 0.f); acc[r].w = fmaxf(acc[r].w, 0.f);
    }
  }

  float4* out4 = (float4*)out;
#pragma unroll
  for (int r = 0; r < 4; ++r) {
    int gr = rowBase + rg * 4 + r;
    if (gr < M) out4[(size_t)gr * NC4 + (colBase >> 2) + cg] = acc[r];
  }

  if (MOUT == 2) {
    // column partial sums over this thread's (valid) 4 rows
    float ps[4] = {0, 0, 0, 0}, pq[4] = {0, 0, 0, 0};
#pragma unroll
    for (int r = 0; r < 4; ++r) {
      int gr = rowBase + rg * 4 + r;
      if (gr < M) {
        ps[0] += acc[r].x; pq[0] += acc[r].x * acc[r].x;
        ps[1] += acc[r].y; pq[1] += acc[r].y * acc[r].y;
        ps[2] += acc[r].z; pq[2] += acc[r].z * acc[r].z;
        ps[3] += acc[r].w; pq[3] += acc[r].w * acc[r].w;
      }
    }
    float* sredS = As;          // [16 rg][64 cols]
    float* sredQ = As + 1024;   // [16 rg][64 cols]
#pragma unroll
    for (int j = 0; j < 4; ++j) {
      sredS[rg * 64 + cg * 4 + j] = ps[j];
      sredQ[rg * 64 + cg * 4 + j] = pq[j];
    }
    __syncthreads();
    if (tid < 64) {
      float s = 0.f;
#pragma unroll
      for (int g = 0; g < 16; ++g) s += sredS[g * 64 + tid];
      atomicAdd(&csum[colBase + tid], s);
    } else if (tid < 128) {
      int c = tid - 64;
      float q = 0.f;
#pragma unroll
      for (int g = 0; g < 16; ++g) q += sredQ[g * 64 + c];
      atomicAdd(&csq[colBase + c], q);
    }
  }
}

// ---------------- launch ----------------

extern "C" void kernel_launch(void* const* d_in, const int* in_sizes, int n_in,
                              void* d_out, int out_size, void* d_ws, size_t ws_size,
                              hipStream_t stream) {
  const float* node_feat = (const float*)d_in[0];
  const int* src = (const int*)d_in[1];
  const int* dst = (const int*)d_in[2];
  const float* W1 = (const float*)d_in[3];
  const float* b1 = (const float*)d_in[4];
  const float* gamma = (const float*)d_in[5];
  const float* beta = (const float*)d_in[6];
  const float* W2 = (const float*)d_in[7];
  const float* b2 = (const float*)d_in[8];
  const float* eps = (const float*)d_in[9];
  const float* Wout = (const float*)d_in[10];
  const float* bout = (const float*)d_in[11];
  float* out = (float*)d_out;

  // workspace layout (16B-aligned slices)
  int* deg = (int*)d_ws;              // 50176 ints
  int* rs = deg + 50176;              // 50176 ints (uses 50001)
  int* cursor = rs + 50176;           // 50176 ints
  int* eidx = cursor + 50176;         // 1600000 ints
  float* zbuf = (float*)(eidx + NE);  // 6.4M floats
  float* hbuf = zbuf + (size_t)NN * HID;
  float* stats = hbuf + (size_t)NN * HID;  // 256 floats: csum|csq

  hipMemsetAsync(deg, 0, NN * sizeof(int), stream);
  const int edgeThreads8 = (NE + 7) / 8;
  const int edgeGrid8 = (edgeThreads8 + 255) / 256;
  k_hist<<<edgeGrid8, 256, 0, stream>>>(dst, deg, NE);
  k_scan<<<1, 1024, 0, stream>>>(deg, rs, cursor, NN);
  k_scatter<<<edgeGrid8, 256, 0, stream>>>(src, dst, cursor, eidx, NE);

  const int aggGrid = (NN * 64 + 255) / 256;  // one wave per node
  const int rowTiles = (NN + 63) / 64;        // 782

  // Ping-pong: per layer, z and h' live in one buffer, x in the other.
  //   agg:   hcur -> zb      GEMM1: zb -> xb      GEMM2: xb -> zb
  const float* hcur = node_feat;
  for (int L = 0; L < 3; ++L) {
    float* zb = (L & 1) ? hbuf : zbuf;
    float* xb = (L & 1) ? zbuf : hbuf;
    k_agg<<<aggGrid, 256, 0, stream>>>(hcur, rs, eidx, eps, L, zb, NN);
    hipMemsetAsync(stats, 0, 256 * sizeof(float), stream);
    // x = z @ W1[L] + b1[L], + column stats
    k_gemm<128, 0, 2><<<dim3(rowTiles, 2), 256, 0, stream>>>(
        zb, W1 + (size_t)L * HID * HID, b1 + (size_t)L * HID, nullptr, nullptr,
        stats, stats + HID, xb, NN);
    // h' = relu( relu(BN(x)) @ W2[L] + b2[L] )
    k_gemm<128, 1, 1><<<dim3(rowTiles, 2), 256, 0, stream>>>(
        xb, W2 + (size_t)L * HID * HID, b2 + (size_t)L * HID,
        gamma + (size_t)L * HID, beta + (size_t)L * HID, stats, stats + HID, zb,
        NN);
    hcur = zb;
  }
  // out = h @ Wout + bout   (hcur == zbuf after 3 layers)
  k_gemm<64, 0, 0><<<dim3(rowTiles, 1), 256, 0, stream>>>(
      hcur, Wout, bout, nullptr, nullptr, nullptr, nullptr, out, NN);
}

// Round 6
// 740.978 us; speedup vs baseline: 4.6135x; 1.3399x over previous
//
#include <hip/hip_runtime.h>

#define NN 50000
#define NE 1600000
#define HID 128
#define NB 196     // dst buckets: dst>>8 -> 0..195 (256 nodes each)
#define BCAP 12288 // per-bucket LDS edge capacity (avg 8163, +40 sigma safe)

// ---------------- CSR build: two-level bucket sort ----------------
// Round-5 evidence: per-edge scatter wrote 103 MB (64B line dilution on random
// 4B stores) at ~0.8 TB/s -> 139 us, unfixable by ILP/TLP. This build makes
// every bulk store either L2-line-local (partition) or coalesced (csr).

__global__ __launch_bounds__(256) void kb_count(const int* __restrict__ dst,
                                                int* __restrict__ gcnt, int E) {
  __shared__ int cnt[NB];
  int tid = threadIdx.x;
  for (int i = tid; i < NB; i += 256) cnt[i] = 0;
  __syncthreads();
  int base = blockIdx.x * 4096;
  for (int i = 0; i < 16; ++i) {
    int e = base + i * 256 + tid;
    if (e < E) atomicAdd(&cnt[dst[e] >> 8], 1);
  }
  __syncthreads();
  for (int i = tid; i < NB; i += 256)
    if (cnt[i]) atomicAdd(&gcnt[i], cnt[i]);
}

__global__ __launch_bounds__(256) void kb_basescan(const int* __restrict__ gcnt,
                                                   int* __restrict__ bbase,
                                                   int* __restrict__ bcur) {
  __shared__ int s[256];
  int tid = threadIdx.x;
  int v = (tid < NB) ? gcnt[tid] : 0;
  s[tid] = v;
  __syncthreads();
  for (int d = 1; d < 256; d <<= 1) {
    int t = (tid >= d) ? s[tid - d] : 0;
    __syncthreads();
    s[tid] += t;
    __syncthreads();
  }
  int incl = s[tid];
  if (tid < NB) {
    bbase[tid] = incl - v;
    bcur[tid] = incl - v;
  }
  if (tid == NB - 1) bbase[NB] = incl;
}

__global__ __launch_bounds__(256) void kb_partition(const int* __restrict__ src,
                                                    const int* __restrict__ dst,
                                                    int* __restrict__ bcur,
                                                    int2* __restrict__ ebuf, int E) {
  __shared__ int cnt[NB];
  __shared__ int sbase[NB];
  int tid = threadIdx.x;
  for (int i = tid; i < NB; i += 256) cnt[i] = 0;
  __syncthreads();
  int base = blockIdx.x * 4096;
  int myd[16], mys[16];
#pragma unroll
  for (int i = 0; i < 16; ++i) {
    int e = base + i * 256 + tid;
    if (e < E) {
      myd[i] = dst[e];
      mys[i] = src[e];
      atomicAdd(&cnt[myd[i] >> 8], 1);
    } else {
      myd[i] = -1;
    }
  }
  __syncthreads();
  for (int i = tid; i < NB; i += 256)
    sbase[i] = cnt[i] ? atomicAdd(&bcur[i], cnt[i]) : 0;
  __syncthreads();
  for (int i = tid; i < NB; i += 256) cnt[i] = 0;  // reuse as rank counter
  __syncthreads();
#pragma unroll
  for (int i = 0; i < 16; ++i) {
    if (myd[i] >= 0) {
      int b = myd[i] >> 8;
      int r = atomicAdd(&cnt[b], 1);
      ebuf[sbase[b] + r] = make_int2(mys[i], myd[i]);
    }
  }
}

// One block per bucket: local CSR (hist -> scan -> LDS scatter), coalesced out.
__global__ __launch_bounds__(256) void kb_csr(const int2* __restrict__ ebuf,
                                              const int* __restrict__ bbase,
                                              int* __restrict__ rs,
                                              int* __restrict__ eidx, int M) {
  __shared__ int cnt[256];
  __shared__ int off[256];
  __shared__ int sbuf[BCAP];
  int tid = threadIdx.x;
  int b = blockIdx.x;
  int lo = bbase[b], hi = bbase[b + 1];
  int n = hi - lo;
  cnt[tid] = 0;
  __syncthreads();
  for (int i = tid; i < n; i += 256) atomicAdd(&cnt[ebuf[lo + i].y & 255], 1);
  __syncthreads();
  int v = cnt[tid];
  off[tid] = v;
  __syncthreads();
  for (int d = 1; d < 256; d <<= 1) {
    int t = (tid >= d) ? off[tid - d] : 0;
    __syncthreads();
    off[tid] += t;
    __syncthreads();
  }
  int excl = off[tid] - v;
  int gnode = b * 256 + tid;
  if (gnode < M) rs[gnode] = lo + excl;
  if (b == NB - 1 && tid == 0) rs[M] = bbase[NB];
  __syncthreads();
  cnt[tid] = excl;  // reuse as cursor
  __syncthreads();
  if (n <= BCAP) {
    for (int i = tid; i < n; i += 256) {
      int2 ed = ebuf[lo + i];
      int r = atomicAdd(&cnt[ed.y & 255], 1);
      sbuf[r] = ed.x;
    }
    __syncthreads();
    for (int i = tid; i < n; i += 256) eidx[lo + i] = sbuf[i];
  } else {  // never expected for this graph; correctness fallback
    for (int i = tid; i < n; i += 256) {
      int2 ed = ebuf[lo + i];
      int r = atomicAdd(&cnt[ed.y & 255], 1);
      eidx[lo + r] = ed.x;
    }
  }
}

// ---------------- aggregation: z = (1+eps)*h + sum_{e: dst=node} h[src_e] --------
// One wave per node; float4 per lane, 2 edges per load instr, 8-edge unroll.

__global__ __launch_bounds__(256) void k_agg(const float* __restrict__ h,
                                             const int* __restrict__ rs,
                                             const int* __restrict__ eidx,
                                             const float* __restrict__ eps, int layer,
                                             float* __restrict__ z, int M) {
  int node = (int)((blockIdx.x * 256 + threadIdx.x) >> 6);
  if (node >= M) return;
  const int lane = threadIdx.x & 63;
  const int half = lane >> 5;
  const int col = lane & 31;

  const float4* h4 = (const float4*)h;
  int e0 = rs[node], e1 = rs[node + 1];

  float4 a0 = make_float4(0.f, 0.f, 0.f, 0.f);
  float4 a1 = make_float4(0.f, 0.f, 0.f, 0.f);
  float4 a2 = make_float4(0.f, 0.f, 0.f, 0.f);
  float4 a3 = make_float4(0.f, 0.f, 0.f, 0.f);

#define ACC4(A, V) \
  A.x += V.x; A.y += V.y; A.z += V.z; A.w += V.w;

  int e = e0 + half;
  for (; e + 6 < e1; e += 8) {
    int s0 = eidx[e];
    int s1 = eidx[e + 2];
    int s2 = eidx[e + 4];
    int s3 = eidx[e + 6];
    float4 v0 = h4[(size_t)s0 * 32 + col];
    float4 v1 = h4[(size_t)s1 * 32 + col];
    float4 v2 = h4[(size_t)s2 * 32 + col];
    float4 v3 = h4[(size_t)s3 * 32 + col];
    ACC4(a0, v0)
    ACC4(a1, v1)
    ACC4(a2, v2)
    ACC4(a3, v3)
  }
  for (; e < e1; e += 2) {
    int s = eidx[e];
    float4 v = h4[(size_t)s * 32 + col];
    ACC4(a0, v)
  }
#undef ACC4

  a0.x += a1.x + a2.x + a3.x;
  a0.y += a1.y + a2.y + a3.y;
  a0.z += a1.z + a2.z + a3.z;
  a0.w += a1.w + a2.w + a3.w;

  a0.x += __shfl_xor(a0.x, 32);
  a0.y += __shfl_xor(a0.y, 32);
  a0.z += __shfl_xor(a0.z, 32);
  a0.w += __shfl_xor(a0.w, 32);

  if (half == 0) {
    float ep = 1.0f + eps[layer];
    float4 hv = h4[(size_t)node * 32 + col];
    float4 o;
    o.x = fmaf(ep, hv.x, a0.x);
    o.y = fmaf(ep, hv.y, a0.y);
    o.z = fmaf(ep, hv.z, a0.z);
    o.w = fmaf(ep, hv.w, a0.w);
    ((float4*)z)[(size_t)node * 32 + col] = o;
  }
}

// ---------------- row-wise GEMM (K=128), 64x64 tile, 4x4 per-thread acc ------
// MIN:  0 = plain input load, 1 = apply BN(scale/shift)+relu while staging
// MOUT: 0 = +bias, 1 = relu(+bias), 2 = +bias and accumulate col sum/sumsq
// in/out must NOT alias (grid.y=2 blocks share input rows).

#define APAD 132

template <int NOUT, int MIN, int MOUT>
__global__ __launch_bounds__(256, 3) void k_gemm(
    const float* __restrict__ in, const float* __restrict__ W,
    const float* __restrict__ bias, const float* __restrict__ gamma,
    const float* __restrict__ beta, float* __restrict__ csum,
    float* __restrict__ csq, float* __restrict__ out, int M) {
  __shared__ float As[64 * APAD];
  __shared__ float Ws[64 * 64];

  const int tid = threadIdx.x;
  const int cg = tid & 15;
  const int rg = tid >> 4;
  const int rowBase = blockIdx.x * 64;
  const int colBase = blockIdx.y * 64;
  constexpr int NC4 = NOUT / 4;

  const int kq_st = tid & 31;
  float sc[4], sh[4];
  if (MIN == 1) {
    float invM = 1.0f / (float)M;
#pragma unroll
    for (int j = 0; j < 4; ++j) {
      int k = kq_st * 4 + j;
      float mu = csum[k] * invM;
      float var = csq[k] * invM - mu * mu;
      float g = gamma[k] * rsqrtf(var + 1e-5f);
      sc[j] = g;
      sh[j] = fmaf(-mu, g, beta[k]);
    }
  }

  const float4* in4 = (const float4*)in;
#pragma unroll
  for (int i = 0; i < 8; ++i) {
    int f = tid + i * 256;
    int row = f >> 5;
    int kq = f & 31;
    int gr = rowBase + row;
    float4 v = make_float4(0.f, 0.f, 0.f, 0.f);
    if (gr < M) v = in4[(size_t)gr * 32 + kq];
    if (MIN == 1) {
      v.x = fmaxf(fmaf(v.x, sc[0], sh[0]), 0.f);
      v.y = fmaxf(fmaf(v.y, sc[1], sh[1]), 0.f);
      v.z = fmaxf(fmaf(v.z, sc[2], sh[2]), 0.f);
      v.w = fmaxf(fmaf(v.w, sc[3], sh[3]), 0.f);
    }
    float* d = &As[row * APAD + kq * 4];
    d[0] = v.x; d[1] = v.y; d[2] = v.z; d[3] = v.w;
  }

  float4 acc[4];
#pragma unroll
  for (int r = 0; r < 4; ++r) acc[r] = make_float4(0.f, 0.f, 0.f, 0.f);

  const float4* Wg4 = (const float4*)W;
  const float4* Ws4 = (const float4*)Ws;

#pragma unroll
  for (int h = 0; h < 2; ++h) {
#pragma unroll
    for (int i = 0; i < 4; ++i) {
      int f = tid + i * 256;
      int kk = f >> 4;
      int cq = f & 15;
      ((float4*)Ws)[kk * 16 + cq] =
          Wg4[(size_t)(h * 64 + kk) * NC4 + (colBase >> 2) + cq];
    }
    __syncthreads();

    const float* A0 = &As[(rg * 4 + 0) * APAD + h * 64];
    const float* A1 = &As[(rg * 4 + 1) * APAD + h * 64];
    const float* A2 = &As[(rg * 4 + 2) * APAD + h * 64];
    const float* A3 = &As[(rg * 4 + 3) * APAD + h * 64];

#pragma unroll 4
    for (int kk = 0; kk < 64; kk += 4) {
      float4 b0 = Ws4[(kk + 0) * 16 + cg];
      float4 b1 = Ws4[(kk + 1) * 16 + cg];
      float4 b2 = Ws4[(kk + 2) * 16 + cg];
      float4 b3 = Ws4[(kk + 3) * 16 + cg];
      float4 a0 = *(const float4*)(A0 + kk);
      float4 a1 = *(const float4*)(A1 + kk);
      float4 a2 = *(const float4*)(A2 + kk);
      float4 a3 = *(const float4*)(A3 + kk);
#define FMA_ROW(r, a)                                                       \
  acc[r].x = fmaf(a.x, b0.x, acc[r].x); acc[r].x = fmaf(a.y, b1.x, acc[r].x); \
  acc[r].x = fmaf(a.z, b2.x, acc[r].x); acc[r].x = fmaf(a.w, b3.x, acc[r].x); \
  acc[r].y = fmaf(a.x, b0.y, acc[r].y); acc[r].y = fmaf(a.y, b1.y, acc[r].y); \
  acc[r].y = fmaf(a.z, b2.y, acc[r].y); acc[r].y = fmaf(a.w, b3.y, acc[r].y); \
  acc[r].z = fmaf(a.x, b0.z, acc[r].z); acc[r].z = fmaf(a.y, b1.z, acc[r].z); \
  acc[r].z = fmaf(a.z, b2.z, acc[r].z); acc[r].z = fmaf(a.w, b3.z, acc[r].z); \
  acc[r].w = fmaf(a.x, b0.w, acc[r].w); acc[r].w = fmaf(a.y, b1.w, acc[r].w); \
  acc[r].w = fmaf(a.z, b2.w, acc[r].w); acc[r].w = fmaf(a.w, b3.w, acc[r].w);
      FMA_ROW(0, a0)
      FMA_ROW(1, a1)
      FMA_ROW(2, a2)
      FMA_ROW(3, a3)
#undef FMA_ROW
    }
    __syncthreads();
  }

  float4 bv = ((const float4*)bias)[(colBase >> 2) + cg];
#pragma unroll
  for (int r = 0; r < 4; ++r) {
    acc[r].x += bv.x; acc[r].y += bv.y; acc[r].z += bv.z; acc[r].w += bv.w;
    if (MOUT == 1) {
      acc[r].x = fmaxf(acc[r].x, 0.f); acc[r].y = fmaxf(acc[r].y, 0.f);
      acc[r].z = fmaxf(acc[r].z, 0.f); acc[r].w = fmaxf(acc[r].w, 0.f);
    }
  }

  float4* out4 = (float4*)out;
#pragma unroll
  for (int r = 0; r < 4; ++r) {
    int gr = rowBase + rg * 4 + r;
    if (gr < M) out4[(size_t)gr * NC4 + (colBase >> 2) + cg] = acc[r];
  }

  if (MOUT == 2) {
    float ps[4] = {0, 0, 0, 0}, pq[4] = {0, 0, 0, 0};
#pragma unroll
    for (int r = 0; r < 4; ++r) {
      int gr = rowBase + rg * 4 + r;
      if (gr < M) {
        ps[0] += acc[r].x; pq[0] += acc[r].x * acc[r].x;
        ps[1] += acc[r].y; pq[1] += acc[r].y * acc[r].y;
        ps[2] += acc[r].z; pq[2] += acc[r].z * acc[r].z;
        ps[3] += acc[r].w; pq[3] += acc[r].w * acc[r].w;
      }
    }
    float* sredS = As;
    float* sredQ = As + 1024;
#pragma unroll
    for (int j = 0; j < 4; ++j) {
      sredS[rg * 64 + cg * 4 + j] = ps[j];
      sredQ[rg * 64 + cg * 4 + j] = pq[j];
    }
    __syncthreads();
    if (tid < 64) {
      float s = 0.f;
#pragma unroll
      for (int g = 0; g < 16; ++g) s += sredS[g * 64 + tid];
      atomicAdd(&csum[colBase + tid], s);
    } else if (tid < 128) {
      int c = tid - 64;
      float q = 0.f;
#pragma unroll
      for (int g = 0; g < 16; ++g) q += sredQ[g * 64 + c];
      atomicAdd(&csq[colBase + c], q);
    }
  }
}

// ---------------- launch ----------------

extern "C" void kernel_launch(void* const* d_in, const int* in_sizes, int n_in,
                              void* d_out, int out_size, void* d_ws, size_t ws_size,
                              hipStream_t stream) {
  const float* node_feat = (const float*)d_in[0];
  const int* src = (const int*)d_in[1];
  const int* dst = (const int*)d_in[2];
  const float* W1 = (const float*)d_in[3];
  const float* b1 = (const float*)d_in[4];
  const float* gamma = (const float*)d_in[5];
  const float* beta = (const float*)d_in[6];
  const float* W2 = (const float*)d_in[7];
  const float* b2 = (const float*)d_in[8];
  const float* eps = (const float*)d_in[9];
  const float* Wout = (const float*)d_in[10];
  const float* bout = (const float*)d_in[11];
  float* out = (float*)d_out;

  // workspace layout (16B-aligned slices)
  int* rs = (int*)d_ws;           // 50176 ints (uses 50001)
  int* gcnt = rs + 50176;         // 256 ints (uses NB)
  int* bbase = gcnt + 256;        // 256 ints (uses NB+1)
  int* bcur = bbase + 256;        // 256 ints
  int* eidx = bcur + 256;         // NE ints
  float* zbuf = (float*)(eidx + NE);       // 6.4M floats
  float* hbuf = zbuf + (size_t)NN * HID;   // 6.4M floats
  float* stats = hbuf + (size_t)NN * HID;  // 256 floats: csum|csq
  int2* ebuf = (int2*)zbuf;  // 12.8MB staging, dead before first k_agg write

  hipMemsetAsync(gcnt, 0, NB * sizeof(int), stream);
  const int partGrid = (NE + 4095) / 4096;  // 391
  kb_count<<<partGrid, 256, 0, stream>>>(dst, gcnt, NE);
  kb_basescan<<<1, 256, 0, stream>>>(gcnt, bbase, bcur);
  kb_partition<<<partGrid, 256, 0, stream>>>(src, dst, bcur, ebuf, NE);
  kb_csr<<<NB, 256, 0, stream>>>(ebuf, bbase, rs, eidx, NN);

  const int aggGrid = (NN * 64 + 255) / 256;  // one wave per node
  const int rowTiles = (NN + 63) / 64;        // 782

  // Ping-pong: agg: hcur -> zb,  GEMM1: zb -> xb,  GEMM2: xb -> zb
  const float* hcur = node_feat;
  for (int L = 0; L < 3; ++L) {
    float* zb = (L & 1) ? hbuf : zbuf;
    float* xb = (L & 1) ? zbuf : hbuf;
    k_agg<<<aggGrid, 256, 0, stream>>>(hcur, rs, eidx, eps, L, zb, NN);
    hipMemsetAsync(stats, 0, 256 * sizeof(float), stream);
    k_gemm<128, 0, 2><<<dim3(rowTiles, 2), 256, 0, stream>>>(
        zb, W1 + (size_t)L * HID * HID, b1 + (size_t)L * HID, nullptr, nullptr,
        stats, stats + HID, xb, NN);
    k_gemm<128, 1, 1><<<dim3(rowTiles, 2), 256, 0, stream>>>(
        xb, W2 + (size_t)L * HID * HID, b2 + (size_t)L * HID,
        gamma + (size_t)L * HID, beta + (size_t)L * HID, stats, stats + HID, zb,
        NN);
    hcur = zb;
  }
  k_gemm<64, 0, 0><<<dim3(rowTiles, 1), 256, 0, stream>>>(
      hcur, Wout, bout, nullptr, nullptr, nullptr, nullptr, out, NN);
}

// Round 7
// 458.893 us; speedup vs baseline: 7.4495x; 1.6147x over previous
//
#include <hip/hip_runtime.h>

#define NN 50000
#define NE 1600000
#define HID 128
#define NB 196     // dst buckets: dst>>8 -> 0..195 (256 nodes each)
#define BCAP 12288 // per-bucket LDS edge capacity

typedef _Float16 half8 __attribute__((ext_vector_type(8)));
typedef float floatx4 __attribute__((ext_vector_type(4)));

// ---------------- CSR build: two-level bucket sort (unchanged, R5-verified) ----

__global__ __launch_bounds__(256) void kb_count(const int* __restrict__ dst,
                                                int* __restrict__ gcnt, int E) {
  __shared__ int cnt[NB];
  int tid = threadIdx.x;
  for (int i = tid; i < NB; i += 256) cnt[i] = 0;
  __syncthreads();
  int base = blockIdx.x * 4096;
  for (int i = 0; i < 16; ++i) {
    int e = base + i * 256 + tid;
    if (e < E) atomicAdd(&cnt[dst[e] >> 8], 1);
  }
  __syncthreads();
  for (int i = tid; i < NB; i += 256)
    if (cnt[i]) atomicAdd(&gcnt[i], cnt[i]);
}

__global__ __launch_bounds__(256) void kb_basescan(const int* __restrict__ gcnt,
                                                   int* __restrict__ bbase,
                                                   int* __restrict__ bcur) {
  __shared__ int s[256];
  int tid = threadIdx.x;
  int v = (tid < NB) ? gcnt[tid] : 0;
  s[tid] = v;
  __syncthreads();
  for (int d = 1; d < 256; d <<= 1) {
    int t = (tid >= d) ? s[tid - d] : 0;
    __syncthreads();
    s[tid] += t;
    __syncthreads();
  }
  int incl = s[tid];
  if (tid < NB) {
    bbase[tid] = incl - v;
    bcur[tid] = incl - v;
  }
  if (tid == NB - 1) bbase[NB] = incl;
}

__global__ __launch_bounds__(256) void kb_partition(const int* __restrict__ src,
                                                    const int* __restrict__ dst,
                                                    int* __restrict__ bcur,
                                                    int2* __restrict__ ebuf, int E) {
  __shared__ int cnt[NB];
  __shared__ int sbase[NB];
  int tid = threadIdx.x;
  for (int i = tid; i < NB; i += 256) cnt[i] = 0;
  __syncthreads();
  int base = blockIdx.x * 4096;
  int myd[16], mys[16];
#pragma unroll
  for (int i = 0; i < 16; ++i) {
    int e = base + i * 256 + tid;
    if (e < E) {
      myd[i] = dst[e];
      mys[i] = src[e];
      atomicAdd(&cnt[myd[i] >> 8], 1);
    } else {
      myd[i] = -1;
    }
  }
  __syncthreads();
  for (int i = tid; i < NB; i += 256)
    sbase[i] = cnt[i] ? atomicAdd(&bcur[i], cnt[i]) : 0;
  __syncthreads();
  for (int i = tid; i < NB; i += 256) cnt[i] = 0;
  __syncthreads();
#pragma unroll
  for (int i = 0; i < 16; ++i) {
    if (myd[i] >= 0) {
      int b = myd[i] >> 8;
      int r = atomicAdd(&cnt[b], 1);
      ebuf[sbase[b] + r] = make_int2(mys[i], myd[i]);
    }
  }
}

__global__ __launch_bounds__(256) void kb_csr(const int2* __restrict__ ebuf,
                                              const int* __restrict__ bbase,
                                              int* __restrict__ rs,
                                              int* __restrict__ eidx, int M) {
  __shared__ int cnt[256];
  __shared__ int off[256];
  __shared__ int sbuf[BCAP];
  int tid = threadIdx.x;
  int b = blockIdx.x;
  int lo = bbase[b], hi = bbase[b + 1];
  int n = hi - lo;
  cnt[tid] = 0;
  __syncthreads();
  for (int i = tid; i < n; i += 256) atomicAdd(&cnt[ebuf[lo + i].y & 255], 1);
  __syncthreads();
  int v = cnt[tid];
  off[tid] = v;
  __syncthreads();
  for (int d = 1; d < 256; d <<= 1) {
    int t = (tid >= d) ? off[tid - d] : 0;
    __syncthreads();
    off[tid] += t;
    __syncthreads();
  }
  int excl = off[tid] - v;
  int gnode = b * 256 + tid;
  if (gnode < M) rs[gnode] = lo + excl;
  if (b == NB - 1 && tid == 0) rs[M] = bbase[NB];
  __syncthreads();
  cnt[tid] = excl;
  __syncthreads();
  if (n <= BCAP) {
    for (int i = tid; i < n; i += 256) {
      int2 ed = ebuf[lo + i];
      int r = atomicAdd(&cnt[ed.y & 255], 1);
      sbuf[r] = ed.x;
    }
    __syncthreads();
    for (int i = tid; i < n; i += 256) eidx[lo + i] = sbuf[i];
  } else {
    for (int i = tid; i < n; i += 256) {
      int2 ed = ebuf[lo + i];
      int r = atomicAdd(&cnt[ed.y & 255], 1);
      eidx[lo + r] = ed.x;
    }
  }
}

// ---------------- fp32 -> fp16 convert (node_feat, once) ----------------

__global__ __launch_bounds__(256) void k_cvt(const float* __restrict__ x,
                                             _Float16* __restrict__ y, int n8) {
  int t = blockIdx.x * 256 + threadIdx.x;
  if (t >= n8) return;
  const float4* x4 = (const float4*)x;
  float4 u = x4[t * 2], v = x4[t * 2 + 1];
  half8 o;
  o[0] = (_Float16)u.x; o[1] = (_Float16)u.y; o[2] = (_Float16)u.z; o[3] = (_Float16)u.w;
  o[4] = (_Float16)v.x; o[5] = (_Float16)v.y; o[6] = (_Float16)v.z; o[7] = (_Float16)v.w;
  ((half8*)y)[t] = o;
}

// ---------------- weight pack: W[k][n] fp32 -> MFMA B-fragment order fp16 ----
// frag idx t = (kb*NCT+ct)*64+lane holds B[kb*32+(lane>>4)*8+j][ct*16+(lane&15)]

__global__ __launch_bounds__(256) void k_pack(const float* __restrict__ W1,
                                              const float* __restrict__ W2,
                                              const float* __restrict__ Wout,
                                              _Float16* __restrict__ wp) {
  int y = blockIdx.y;
  const float* W;
  _Float16* dst;
  int NCT;
  if (y < 3) { W = W1 + (size_t)y * 16384; dst = wp + y * 16384; NCT = 8; }
  else if (y < 6) { W = W2 + (size_t)(y - 3) * 16384; dst = wp + 49152 + (y - 3) * 16384; NCT = 8; }
  else { W = Wout; dst = wp + 98304; NCT = 4; }
  int t = blockIdx.x * 256 + threadIdx.x;
  if (t >= 4 * NCT * 64) return;
  int lane = t & 63;
  int ct = (t >> 6) % NCT;
  int kb = t / (64 * NCT);
  int n = ct * 16 + (lane & 15);
  int k0 = kb * 32 + (lane >> 4) * 8;
  int N = NCT * 16;
#pragma unroll
  for (int j = 0; j < 8; ++j) dst[t * 8 + j] = (_Float16)W[(k0 + j) * N + n];
}

// ---------------- aggregation (fp16 gather, fp32 accumulate) ----------------
// One wave per node; 16 lanes per 128-half row => 4 edges per load instr;
// 16-edge unroll (4 loads in flight). R6 profile: agg was byte/line-bound at
// 3.7 TB/s on 512B rows — fp16 halves both bytes and line count.

__global__ __launch_bounds__(256) void k_agg16(const _Float16* __restrict__ h,
                                               const int* __restrict__ rs,
                                               const int* __restrict__ eidx,
                                               const float* __restrict__ eps,
                                               int layer,
                                               _Float16* __restrict__ z, int M) {
  int node = (int)((blockIdx.x * 256 + threadIdx.x) >> 6);
  if (node >= M) return;
  const int lane = threadIdx.x & 63;
  const int slot = lane >> 4;
  const int c8 = lane & 15;
  const half8* h8 = (const half8*)h;
  int e0 = rs[node], e1 = rs[node + 1];
  float a0[8] = {0, 0, 0, 0, 0, 0, 0, 0};
  float a1[8] = {0, 0, 0, 0, 0, 0, 0, 0};
  float a2[8] = {0, 0, 0, 0, 0, 0, 0, 0};
  float a3[8] = {0, 0, 0, 0, 0, 0, 0, 0};
  int e = e0 + slot;
  for (; e + 12 < e1; e += 16) {
    int s0 = eidx[e];
    int s1 = eidx[e + 4];
    int s2 = eidx[e + 8];
    int s3 = eidx[e + 12];
    half8 v0 = h8[s0 * 16 + c8];
    half8 v1 = h8[s1 * 16 + c8];
    half8 v2 = h8[s2 * 16 + c8];
    half8 v3 = h8[s3 * 16 + c8];
#pragma unroll
    for (int j = 0; j < 8; ++j) {
      a0[j] += (float)v0[j];
      a1[j] += (float)v1[j];
      a2[j] += (float)v2[j];
      a3[j] += (float)v3[j];
    }
  }
  for (; e < e1; e += 4) {
    int s = eidx[e];
    half8 v = h8[s * 16 + c8];
#pragma unroll
    for (int j = 0; j < 8; ++j) a0[j] += (float)v[j];
  }
#pragma unroll
  for (int j = 0; j < 8; ++j) a0[j] += a1[j] + a2[j] + a3[j];
#pragma unroll
  for (int j = 0; j < 8; ++j) {
    a0[j] += __shfl_xor(a0[j], 16);
    a0[j] += __shfl_xor(a0[j], 32);
  }
  if (slot == 0) {
    float ep = 1.0f + eps[layer];
    half8 hv = h8[node * 16 + c8];
    half8 o;
#pragma unroll
    for (int j = 0; j < 8; ++j) o[j] = (_Float16)fmaf(ep, (float)hv[j], a0[j]);
    ((half8*)z)[node * 16 + c8] = o;
  }
}

// ---------------- MFMA GEMM: 64 rows x (NCT*16) cols per block, K=128 -------
// 4 waves, each 16 rows x full N. A staged in LDS (stride 136 halves);
// B read from packed fragments (coalesced 16B/lane, L1/L2-resident).
// MIN:  1 = BN(scale/shift)+relu applied while staging input
// MOUT: 0 = +bias fp32 out; 1 = relu(+bias) fp16 out; 2 = +bias fp16 out + stats

template <int NCT, int MIN, int MOUT>
__global__ __launch_bounds__(256) void k_mgemm(
    const _Float16* __restrict__ in, const _Float16* __restrict__ Wp,
    const float* __restrict__ bias, const float* __restrict__ gamma,
    const float* __restrict__ beta, float* __restrict__ csum,
    float* __restrict__ csq, void* __restrict__ outv, int M) {
  __shared__ _Float16 As[64 * 136];
  __shared__ float sredS[4 * 128];
  __shared__ float sredQ[4 * 128];
  const int tid = threadIdx.x;
  const int wid = tid >> 6;
  const int lane = tid & 63;
  const int Am = lane & 15;
  const int quad = lane >> 4;
  const int blockRow = blockIdx.x * 64;
  const int c8 = tid & 15;  // constant across staging iters (256 % 16 == 0)

  float sc[8], sh[8];
  if (MIN == 1) {
    const float invM = 1.0f / (float)M;
#pragma unroll
    for (int j = 0; j < 8; ++j) {
      int k = c8 * 8 + j;
      float mu = csum[k] * invM;
      float var = csq[k] * invM - mu * mu;
      float g = gamma[k] * rsqrtf(var + 1e-5f);
      sc[j] = g;
      sh[j] = fmaf(-mu, g, beta[k]);
    }
  }

  // stage A (64 rows x 128 halves)
#pragma unroll
  for (int i = 0; i < 4; ++i) {
    int f = tid + i * 256;
    int row = f >> 4;
    int gr = blockRow + row;
    half8 v = {0, 0, 0, 0, 0, 0, 0, 0};
    if (gr < M) {
      v = *(const half8*)(in + (size_t)gr * 128 + c8 * 8);
      if (MIN == 1) {
#pragma unroll
        for (int j = 0; j < 8; ++j) {
          float x = fmaxf(fmaf((float)v[j], sc[j], sh[j]), 0.f);
          v[j] = (_Float16)x;
        }
      }
    }
    *(half8*)(As + row * 136 + c8 * 8) = v;
  }
  __syncthreads();

  floatx4 acc[NCT];
#pragma unroll
  for (int ct = 0; ct < NCT; ++ct) acc[ct] = (floatx4){0.f, 0.f, 0.f, 0.f};

  const half8* wp8 = (const half8*)Wp;
#pragma unroll
  for (int kb = 0; kb < 4; ++kb) {
    half8 a = *(const half8*)(As + (wid * 16 + Am) * 136 + kb * 32 + quad * 8);
#pragma unroll
    for (int ct = 0; ct < NCT; ++ct) {
      half8 b = wp8[(kb * NCT + ct) * 64 + lane];
      acc[ct] = __builtin_amdgcn_mfma_f32_16x16x32_f16(a, b, acc[ct], 0, 0, 0);
    }
  }

  // epilogue: C/D layout col=lane&15, row=quad*4+reg (per 16x16 tile)
  const int r0 = blockRow + wid * 16 + quad * 4;
  if (MOUT == 0) {
    float* out = (float*)outv;
#pragma unroll
    for (int ct = 0; ct < NCT; ++ct) {
      float bv = bias[ct * 16 + Am];
#pragma unroll
      for (int reg = 0; reg < 4; ++reg) {
        int gr = r0 + reg;
        if (gr < M) out[(size_t)gr * (NCT * 16) + ct * 16 + Am] = acc[ct][reg] + bv;
      }
    }
  } else {
    _Float16* out = (_Float16*)outv;
#pragma unroll
    for (int ct = 0; ct < NCT; ++ct) {
      float bv = bias[ct * 16 + Am];
      float ps = 0.f, pq = 0.f;
#pragma unroll
      for (int reg = 0; reg < 4; ++reg) {
        int gr = r0 + reg;
        float x = acc[ct][reg] + bv;
        if (MOUT == 1) x = fmaxf(x, 0.f);
        if (gr < M) {
          out[(size_t)gr * (NCT * 16) + ct * 16 + Am] = (_Float16)x;
          if (MOUT == 2) {
            ps += x;
            pq += x * x;
          }
        }
      }
      if (MOUT == 2) {
        ps += __shfl_xor(ps, 16);
        ps += __shfl_xor(ps, 32);
        pq += __shfl_xor(pq, 16);
        pq += __shfl_xor(pq, 32);
        if (lane < 16) {
          sredS[wid * 128 + ct * 16 + lane] = ps;
          sredQ[wid * 128 + ct * 16 + lane] = pq;
        }
      }
    }
    if (MOUT == 2) {
      __syncthreads();
      if (tid < 128) {
        float s = 0.f;
#pragma unroll
        for (int w = 0; w < 4; ++w) s += sredS[w * 128 + tid];
        atomicAdd(&csum[tid], s);
      } else {
        int c = tid - 128;
        float q = 0.f;
#pragma unroll
        for (int w = 0; w < 4; ++w) q += sredQ[w * 128 + c];
        atomicAdd(&csq[c], q);
      }
    }
  }
}

// ---------------- launch ----------------

extern "C" void kernel_launch(void* const* d_in, const int* in_sizes, int n_in,
                              void* d_out, int out_size, void* d_ws, size_t ws_size,
                              hipStream_t stream) {
  const float* node_feat = (const float*)d_in[0];
  const int* src = (const int*)d_in[1];
  const int* dst = (const int*)d_in[2];
  const float* W1 = (const float*)d_in[3];
  const float* b1 = (const float*)d_in[4];
  const float* gamma = (const float*)d_in[5];
  const float* beta = (const float*)d_in[6];
  const float* W2 = (const float*)d_in[7];
  const float* b2 = (const float*)d_in[8];
  const float* eps = (const float*)d_in[9];
  const float* Wout = (const float*)d_in[10];
  const float* bout = (const float*)d_in[11];
  float* out = (float*)d_out;

  // workspace layout
  int* rs = (int*)d_ws;          // 50176 ints
  int* gcnt = rs + 50176;        // 256
  int* bbase = gcnt + 256;       // 256
  int* bcur = bbase + 256;       // 256
  int* eidx = bcur + 256;        // NE
  _Float16* b0 = (_Float16*)(eidx + NE);  // h   (6.4M halves)
  _Float16* bz = b0 + (size_t)NN * HID;   // z
  _Float16* bx = bz + (size_t)NN * HID;   // x
  _Float16* wp = bx + (size_t)NN * HID;   // packed weights (106496 halves)
  float* stats = (float*)(wp + 106496);   // 256 floats: csum|csq
  int2* ebuf = (int2*)bz;  // 12.8MB staging; dead before first k_agg16 write

  // h0 = fp16(node_feat); pack weights
  k_cvt<<<(NN * HID / 8 + 255) / 256, 256, 0, stream>>>(node_feat, b0, NN * HID / 8);
  k_pack<<<dim3(8, 7), 256, 0, stream>>>(W1, W2, Wout, wp);

  // CSR build
  hipMemsetAsync(gcnt, 0, NB * sizeof(int), stream);
  const int partGrid = (NE + 4095) / 4096;
  kb_count<<<partGrid, 256, 0, stream>>>(dst, gcnt, NE);
  kb_basescan<<<1, 256, 0, stream>>>(gcnt, bbase, bcur);
  kb_partition<<<partGrid, 256, 0, stream>>>(src, dst, bcur, ebuf, NE);
  kb_csr<<<NB, 256, 0, stream>>>(ebuf, bbase, rs, eidx, NN);

  const int aggGrid = (NN * 64 + 255) / 256;  // one wave per node
  const int rowTiles = (NN + 63) / 64;        // 782

  // fixed roles every layer: agg: b0->bz, gemm1: bz->bx (+stats), gemm2: bx->b0
  for (int L = 0; L < 3; ++L) {
    k_agg16<<<aggGrid, 256, 0, stream>>>(b0, rs, eidx, eps, L, bz, NN);
    hipMemsetAsync(stats, 0, 256 * sizeof(float), stream);
    k_mgemm<8, 0, 2><<<rowTiles, 256, 0, stream>>>(
        bz, wp + L * 16384, b1 + (size_t)L * HID, nullptr, nullptr,
        stats, stats + HID, bx, NN);
    k_mgemm<8, 1, 1><<<rowTiles, 256, 0, stream>>>(
        bx, wp + 49152 + L * 16384, b2 + (size_t)L * HID,
        gamma + (size_t)L * HID, beta + (size_t)L * HID,
        stats, stats + HID, b0, NN);
  }
  // out = h @ Wout + bout (fp32 out)
  k_mgemm<4, 0, 0><<<rowTiles, 256, 0, stream>>>(
      b0, wp + 98304, bout, nullptr, nullptr, nullptr, nullptr, out, NN);
}